// Round 6
// baseline (402.234 us; speedup 1.0000x reference)
//
#include <hip/hip_runtime.h>
#include <hip/hip_bf16.h>

// EGA layer (GAT-like, GLOBAL per-head softmax over edges) on MI355X.
// Pipeline:
//   packw -> MFMA split-GEMM (scores ONLY, no Wh store) -> edge score pass
//   (writes t-buffer + online (m,l) partials) -> finalize -> mark_t (COALESCED
//   t-buffer threshold pass; no gathers) -> whrows (MFMA bf16x3 Wh recompute
//   for marked cols only) -> acc_t (scatter for passing edges).
// Rationale: every 800K x 4-gather edge pass costs 70-140us on this chip
// (latency-bound, all PMCs idle -- r5 mark = 141us). The t-buffer costs ~6us
// of coalesced streaming and eliminates one full gather pass.
// Worst case (flat scores) degrades to one extra full MFMA GEMM: bounded.

#define N_NODES 50000
#define N_EDGES 800000
#define IN_DIM  256
#define OUT_DIM 64
#define HEADS   8
#define NCOL    (HEADS * OUT_DIM)   // 512
#define NBLK_RED 2048               // partial-reduction blocks for edge softmax
#define LN_W_EPS (-20.72326584f)    // ln(1e-9) skip threshold

typedef __attribute__((ext_vector_type(8))) short short8;   // 8 x bf16 (4 VGPRs)
typedef __attribute__((ext_vector_type(4))) float f32x4;

// RNE bf16 hi + trunc bf16 lo split of 2 floats -> packed u32s (lane-order j, j+1)
__device__ __forceinline__ void bf16_split2(float x0, float x1,
                                            unsigned& hi, unsigned& lo)
{
    unsigned u0 = __float_as_uint(x0), u1 = __float_as_uint(x1);
    unsigned r0 = u0 + 0x7FFFu + ((u0 >> 16) & 1u);   // RNE to bf16
    unsigned r1 = u1 + 0x7FFFu + ((u1 >> 16) & 1u);
    float h0 = __uint_as_float(r0 & 0xFFFF0000u);
    float h1 = __uint_as_float(r1 & 0xFFFF0000u);
    hi = (r0 >> 16) | (r1 & 0xFFFF0000u);
    unsigned l0 = __float_as_uint(x0 - h0);           // residual, trunc to bf16
    unsigned l1 = __float_as_uint(x1 - h1);
    lo = (l0 >> 16) | (l1 & 0xFFFF0000u);
}

// ---------------------------------------------------------------------------
// Pack W (fp32 [8][256][64]) into B-fragment layout, bf16 hi/lo.
// B fragment for mfma_16x16x32: lane l -> col=l&15, k=(l>>4)*8+j  => a wave's
// fragment read is 1KB contiguous. Total 512 KB, stays L2-resident.
// ---------------------------------------------------------------------------
__global__ __launch_bounds__(256) void packw_kernel(
    const float* __restrict__ W, short* __restrict__ wp)
{
    const int ct = blockIdx.x;            // 0..31
    const int h  = ct >> 2;               // head (4 col-tiles per head)
    #pragma unroll
    for (int it = 0; it < 2; ++it) {
        const int i  = threadIdx.x + it * 256;   // 512 items: (k8, c)
        const int k8 = i >> 4;
        const int c  = i & 15;
        const int o  = (ct & 3) * 16 + c;
        const float* src = W + (size_t)h * IN_DIM * OUT_DIM
                             + (size_t)k8 * 8 * OUT_DIM + o;
        unsigned hi[4], lo[4];
        #pragma unroll
        for (int p = 0; p < 4; ++p) {
            float x0 = src[(2 * p) * OUT_DIM];
            float x1 = src[(2 * p + 1) * OUT_DIM];
            bf16_split2(x0, x1, hi[p], lo[p]);
        }
        uint4 vh = make_uint4(hi[0], hi[1], hi[2], hi[3]);
        uint4 vl = make_uint4(lo[0], lo[1], lo[2], lo[3]);
        *(uint4*)(wp + (((size_t)(ct * 2 + 0) * 32 + k8) * 128) + c * 8) = vh;
        *(uint4*)(wp + (((size_t)(ct * 2 + 1) * 32 + k8) * 128) + c * 8) = vl;
    }
}

// ---------------------------------------------------------------------------
// MFMA GEMM, SCORES ONLY. 512 threads = 8 waves; wave == head; one 64-row
// x-panel staged ONCE per block (serves all 8 heads), bf16 hi/lo, XOR-swizzle.
// __launch_bounds__(512,2): 256-reg budget AND 2 blocks/CU = 4 waves/SIMD.
// Scores staged in LDS, float4 stores.
// ---------------------------------------------------------------------------
__global__ __launch_bounds__(512, 2) void gemm_kernel(
    const float* __restrict__ x, const short* __restrict__ wp,
    const float* __restrict__ b, const float* __restrict__ a,
    float* __restrict__ s_src, float* __restrict__ s_dst)
{
    // [mi(4)][s(2)][k8(32)][r(16)][j(8)] halfs, 16B chunk index XOR-swizzled
    __shared__ __align__(16) short As[32768];        // 64 KB
    __shared__ __align__(16) float s_tmp[2][64][8];  // 4 KB score staging

    const int row0 = blockIdx.x * 64;
    const int tid  = threadIdx.x;
    const int lane = tid & 63;
    const int head = tid >> 6;            // wave == head 0..7
    const int r16  = lane & 15;
    const int kq   = lane >> 4;

    // ---- prefetch B[ks=0] before the fill: L2 latency hides under fill ----
    const short* pB = wp + (size_t)kq * 128 + (size_t)r16 * 8;
    #define LD_B(ni, s, ks) \
        (*(const short8*)(pB + ((((size_t)(head * 4 + (ni)) * 2 + (s)) * 32 + 4 * (ks)) * 128)))
    short8 Bh[2][4], Bl[2][4];
    #pragma unroll
    for (int ni = 0; ni < 4; ++ni) { Bh[0][ni] = LD_B(ni, 0, 0); Bl[0][ni] = LD_B(ni, 1, 0); }

    // ---- fill LDS: x panel -> bf16 hi/lo fragment layout (once per block) ----
    #pragma unroll
    for (int q = 0; q < 4; ++q) {
        const int item = q * 512 + tid;           // 2048 items: (row, kc)
        const int row  = item >> 5;               // 0..63
        const int kc   = item & 31;               // K-chunk of 8
        const int grow = row0 + row;
        f32x4 v0 = {0.f, 0.f, 0.f, 0.f}, v1 = {0.f, 0.f, 0.f, 0.f};
        if (grow < N_NODES) {
            v0 = *(const f32x4*)(x + (size_t)grow * IN_DIM + kc * 8);
            v1 = *(const f32x4*)(x + (size_t)grow * IN_DIM + kc * 8 + 4);
        }
        unsigned hi[4], lo[4];
        bf16_split2(v0.x, v0.y, hi[0], lo[0]);
        bf16_split2(v0.z, v0.w, hi[1], lo[1]);
        bf16_split2(v1.x, v1.y, hi[2], lo[2]);
        bf16_split2(v1.z, v1.w, hi[3], lo[3]);
        const int mi  = row >> 4, rr = row & 15;
        const int swz = rr ^ (kc & 15);
        uint4 vh = make_uint4(hi[0], hi[1], hi[2], hi[3]);
        uint4 vl = make_uint4(lo[0], lo[1], lo[2], lo[3]);
        *(uint4*)((char*)As + ((((mi * 2 + 0) * 32 + kc) * 16 + swz) * 16)) = vh;
        *(uint4*)((char*)As + ((((mi * 2 + 1) * 32 + kc) * 16 + swz) * 16)) = vl;
    }
    __syncthreads();

    // ---- K-loop (verified r1/r2 structure) ----
    f32x4 acc[4][4] = {};

    #define LD_A(mi, s, ks) \
        (*(const short8*)((const char*)As + \
            (((((mi) * 2 + (s)) * 32 + (4 * (ks) + kq)) * 16 + \
              (r16 ^ ((4 * ((ks) & 3) + kq)))) * 16)))

    short8 Ah[2][4], Al[2][4];
    #pragma unroll
    for (int mi = 0; mi < 4; ++mi) { Ah[0][mi] = LD_A(mi, 0, 0); Al[0][mi] = LD_A(mi, 1, 0); }

    #pragma unroll
    for (int ks = 0; ks < 8; ++ks) {
        const int cur = ks & 1, nxt = cur ^ 1;
        if (ks < 7) {
            #pragma unroll
            for (int ni = 0; ni < 4; ++ni) {
                Bh[nxt][ni] = LD_B(ni, 0, ks + 1);
                Bl[nxt][ni] = LD_B(ni, 1, ks + 1);
            }
            #pragma unroll
            for (int mi = 0; mi < 4; ++mi) {
                Ah[nxt][mi] = LD_A(mi, 0, ks + 1);
                Al[nxt][mi] = LD_A(mi, 1, ks + 1);
            }
        }
        #pragma unroll
        for (int mi = 0; mi < 4; ++mi)
            #pragma unroll
            for (int ni = 0; ni < 4; ++ni) {
                acc[mi][ni] = __builtin_amdgcn_mfma_f32_16x16x32_bf16(
                    Ah[cur][mi], Bh[cur][ni], acc[mi][ni], 0, 0, 0);
                acc[mi][ni] = __builtin_amdgcn_mfma_f32_16x16x32_bf16(
                    Ah[cur][mi], Bl[cur][ni], acc[mi][ni], 0, 0, 0);
                acc[mi][ni] = __builtin_amdgcn_mfma_f32_16x16x32_bf16(
                    Al[cur][mi], Bh[cur][ni], acc[mi][ni], 0, 0, 0);
            }
    }
    #undef LD_A
    #undef LD_B

    // ---- epilogue: fused score dot-products only (no Wh store) ----
    // C layout (verified): col = lane&15, row = (lane>>4)*4 + reg
    const int n0 = head * 64;
    float bias[4], avs[4], avd[4];
    #pragma unroll
    for (int ni = 0; ni < 4; ++ni) {
        bias[ni] = b[n0 + ni * 16 + r16];
        avs[ni]  = a[head * 128 + ni * 16 + r16];
        avd[ni]  = a[head * 128 + 64 + ni * 16 + r16];
    }
    #pragma unroll
    for (int mi = 0; mi < 4; ++mi) {
        #pragma unroll
        for (int reg = 0; reg < 4; ++reg) {
            float ps = 0.f, pd = 0.f;
            #pragma unroll
            for (int ni = 0; ni < 4; ++ni) {
                const float v = acc[mi][ni][reg] + bias[ni];
                ps += v * avs[ni];
                pd += v * avd[ni];
            }
            ps += __shfl_xor(ps, 1); pd += __shfl_xor(pd, 1);
            ps += __shfl_xor(ps, 2); pd += __shfl_xor(pd, 2);
            ps += __shfl_xor(ps, 4); pd += __shfl_xor(pd, 4);
            ps += __shfl_xor(ps, 8); pd += __shfl_xor(pd, 8);
            if (r16 == 0) {
                const int rloc = mi * 16 + kq * 4 + reg;
                s_tmp[0][rloc][head] = ps;
                s_tmp[1][rloc][head] = pd;
            }
        }
    }
    __syncthreads();
    if (tid < 256) {
        const int r   = tid & 63;
        const int sel = tid >> 6;            // 0..3: src-lo, src-hi, dst-lo, dst-hi
        const int gr  = row0 + r;
        if (gr < N_NODES) {
            float* dst = (sel < 2) ? s_src : s_dst;
            *(float4*)(dst + (size_t)gr * 8 + (sel & 1) * 4) =
                *(const float4*)&s_tmp[sel >> 1][r][(sel & 1) * 4];
        }
    }
}

// ---------------------------------------------------------------------------
// Edge score pass: lane-pair split (even lane: heads 0-3, odd: heads 4-7).
// Per edge-pair: ONE float4 gather per table per lane + half the per-lane
// online-softmax VALU. Writes t[8] coalesced to tbuf (if non-null) and
// per-block online (m,l) partials.
// ---------------------------------------------------------------------------
__global__ __launch_bounds__(256) void edge_score_kernel(
    const int* __restrict__ ei, const float* __restrict__ s_src,
    const float* __restrict__ s_dst, float* __restrict__ tbuf,
    float* __restrict__ partial)
{
    const int tid  = threadIdx.x;
    const int half = tid & 1;            // heads half*4 .. half*4+3

    float m[4], l[4];
    #pragma unroll
    for (int i = 0; i < 4; ++i) { m[i] = -1e30f; l[i] = 0.f; }

    for (int p = blockIdx.x * 128 + (tid >> 1); p < N_EDGES; p += gridDim.x * 128) {
        const int row = ei[p];
        const int col = ei[N_EDGES + p];
        const f32x4 s = *(const f32x4*)(s_src + row * 8 + half * 4);
        const f32x4 d = *(const f32x4*)(s_dst + col * 8 + half * 4);
        float t[4];
        #pragma unroll
        for (int i = 0; i < 4; ++i) {
            float v = s[i] + d[i];
            t[i] = v > 0.f ? v : 0.01f * v;       // leaky_relu 0.01
        }
        if (tbuf)
            *(float4*)(tbuf + (size_t)p * 8 + half * 4) =
                make_float4(t[0], t[1], t[2], t[3]);
        #pragma unroll
        for (int i = 0; i < 4; ++i) {
            const float mn = fmaxf(m[i], t[i]);
            l[i] = l[i] * __expf(m[i] - mn) + __expf(t[i] - mn);
            m[i] = mn;
        }
    }

    // block reduce; parity-preserving strides keep head mapping intact
    __shared__ float red[8][256];
    #pragma unroll
    for (int i = 0; i < 4; ++i) { red[i][tid] = m[i]; red[4 + i][tid] = l[i]; }
    __syncthreads();
    for (int s = 128; s >= 2; s >>= 1) {
        if (tid < s) {
            #pragma unroll
            for (int i = 0; i < 4; ++i) {
                const float mo = red[i][tid + s], lo = red[4 + i][tid + s];
                const float mm = red[i][tid],     ll = red[4 + i][tid];
                const float mn = fmaxf(mm, mo);
                red[4 + i][tid] = ll * __expf(mm - mn) + lo * __expf(mo - mn);
                red[i][tid]     = mn;
            }
        }
        __syncthreads();
    }
    if (tid < 2) {
        #pragma unroll
        for (int i = 0; i < 4; ++i) {
            partial[blockIdx.x * 16 + tid * 4 + i]     = red[i][tid];
            partial[blockIdx.x * 16 + 8 + tid * 4 + i] = red[4 + i][tid];
        }
    }
}

// ---------------------------------------------------------------------------
// Merge partials. coef[h]=M_h, coef[8+h]=g_h/L_h, coef[16+h]=skip cutoff.
// ---------------------------------------------------------------------------
__global__ __launch_bounds__(256) void finalize_kernel(
    const float* __restrict__ partial, const float* __restrict__ gate,
    float* __restrict__ coef, int nblk)
{
    const int t = threadIdx.x;
    const int h = t & 7;
    const int j = t >> 3;                 // 0..31
    float m = -1e30f, l = 0.f;
    for (int bk = j; bk < nblk; bk += 32) {
        const float mb = partial[bk * 16 + h];
        const float lb = partial[bk * 16 + 8 + h];
        const float mn = fmaxf(m, mb);
        l = l * __expf(m - mn) + lb * __expf(mb - mn);
        m = mn;
    }
    __shared__ float rm[256], rl[256];
    rm[t] = m; rl[t] = l;
    __syncthreads();
    for (int s = 128; s >= 8; s >>= 1) {
        if (t < s) {
            const float mo = rm[t + s], lo = rl[t + s];
            const float mn = fmaxf(rm[t], mo);
            rl[t] = rl[t] * __expf(rm[t] - mn) + lo * __expf(mo - mn);
            rm[t] = mn;
        }
        __syncthreads();
    }
    if (t < 8) {
        float gm = gate[0];
        for (int i = 1; i < 8; ++i) gm = fmaxf(gm, gate[i]);
        float gs = 0.f;
        for (int i = 0; i < 8; ++i) gs += __expf(gate[i] - gm);
        const float g = __expf(gate[t] - gm) / gs;
        const float C = g / rl[t];
        coef[t]      = rm[t];
        coef[8 + t]  = C;
        coef[16 + t] = rm[t] + LN_W_EPS - __logf(C);   // t >= cut  <=>  w >= eps
    }
}

// ---------------------------------------------------------------------------
// mark_t: COALESCED threshold pass over tbuf (no gathers -- r5's gather-mark
// cost 141us with all PMCs idle). Reads t[8] + col per edge streaming;
// appends passing edges to elist (wave-aggregated) and compacts their cols
// into nlist exactly once via atomicExch on colflag.
// ---------------------------------------------------------------------------
__global__ __launch_bounds__(256) void mark_t_kernel(
    const int* __restrict__ ei, const float* __restrict__ tbuf,
    const float* __restrict__ coef, int* __restrict__ elist,
    int* __restrict__ colflag, int* __restrict__ ecount,
    int* __restrict__ ncount, int* __restrict__ nlist)
{
    __shared__ float cCut[8];
    if (threadIdx.x < 8) cCut[threadIdx.x] = coef[16 + threadIdx.x];
    __syncthreads();

    const int e = blockIdx.x * 256 + threadIdx.x;
    bool pass = false;
    int col = 0;
    if (e < N_EDGES) {
        col = ei[N_EDGES + e];                    // coalesced
        const float4 t0 = *(const float4*)(tbuf + (size_t)e * 8);
        const float4 t1 = *(const float4*)(tbuf + (size_t)e * 8 + 4);
        pass = (t0.x >= cCut[0]) | (t0.y >= cCut[1]) |
               (t0.z >= cCut[2]) | (t0.w >= cCut[3]) |
               (t1.x >= cCut[4]) | (t1.y >= cCut[5]) |
               (t1.z >= cCut[6]) | (t1.w >= cCut[7]);
    }

    const unsigned long long mask = __ballot(pass);
    if (mask) {
        const int lane   = threadIdx.x & 63;
        const int leader = (int)__builtin_ctzll(mask);
        int base = 0;
        if (lane == leader) base = atomicAdd(ecount, (int)__popcll(mask));
        base = __shfl(base, leader);
        if (pass) {
            const int rank = (int)__popcll(mask & ((1ULL << lane) - 1ULL));
            elist[base + rank] = e;
            if (atomicExch(&colflag[col], 1) == 0) {
                const int ni = atomicAdd(ncount, 1);
                nlist[ni] = col;
            }
        }
    }
}

// ---------------------------------------------------------------------------
// Fallback mark (no tbuf space): r5-verified gather version.
// ---------------------------------------------------------------------------
__global__ __launch_bounds__(256) void mark_kernel(
    const int* __restrict__ ei, const float* __restrict__ s_src,
    const float* __restrict__ s_dst, const float* __restrict__ coef,
    int* __restrict__ elist, int* __restrict__ colflag,
    int* __restrict__ ecount, int* __restrict__ ncount, int* __restrict__ nlist)
{
    __shared__ float cCut[8];
    if (threadIdx.x < 8) cCut[threadIdx.x] = coef[16 + threadIdx.x];
    __syncthreads();

    const int e = blockIdx.x * 256 + threadIdx.x;
    bool pass = false;
    int col = 0;
    if (e < N_EDGES) {
        const int row = ei[e];
        col = ei[N_EDGES + e];
        const float4 s0 = *(const float4*)(s_src + row * 8);
        const float4 s1 = *(const float4*)(s_src + row * 8 + 4);
        const float4 d0 = *(const float4*)(s_dst + col * 8);
        const float4 d1 = *(const float4*)(s_dst + col * 8 + 4);
        float t[8] = { s0.x + d0.x, s0.y + d0.y, s0.z + d0.z, s0.w + d0.w,
                       s1.x + d1.x, s1.y + d1.y, s1.z + d1.z, s1.w + d1.w };
        #pragma unroll
        for (int h = 0; h < 8; ++h) {
            t[h] = t[h] > 0.f ? t[h] : 0.01f * t[h];
            pass |= (t[h] >= cCut[h]);
        }
    }

    const unsigned long long mask = __ballot(pass);
    if (mask) {
        const int lane   = threadIdx.x & 63;
        const int leader = (int)__builtin_ctzll(mask);
        int base = 0;
        if (lane == leader) base = atomicAdd(ecount, (int)__popcll(mask));
        base = __shfl(base, leader);
        if (pass) {
            const int rank = (int)__popcll(mask & ((1ULL << lane) - 1ULL));
            elist[base + rank] = e;
            if (atomicExch(&colflag[col], 1) == 0) {
                const int ni = atomicAdd(ncount, 1);
                nlist[ni] = col;
            }
        }
    }
}

// ---------------------------------------------------------------------------
// Wh recompute for marked cols only -- SAME verified MFMA bf16x3 block as the
// score GEMM, row indices indirected through the compacted nlist. Early exit
// past ncount. Wh stored PERMUTED (element (h,o) at h*64 + (o&15)*4 + (o>>4)).
// ---------------------------------------------------------------------------
__global__ __launch_bounds__(512, 2) void whrows_kernel(
    const float* __restrict__ x, const short* __restrict__ wp,
    const float* __restrict__ b, const int* __restrict__ nlist,
    const int* __restrict__ ncount, float* __restrict__ Wh)
{
    __shared__ __align__(16) short As[32768];   // 64 KB
    __shared__ int nl_sh[64];

    const int nc   = *ncount;
    const int row0 = blockIdx.x * 64;
    if (row0 >= nc) return;

    const int tid  = threadIdx.x;
    const int lane = tid & 63;
    const int head = tid >> 6;            // wave == head 0..7
    const int r16  = lane & 15;
    const int kq   = lane >> 4;

    if (tid < 64) {
        const int idx = row0 + tid;
        nl_sh[tid] = (idx < nc) ? nlist[idx] : -1;
    }

    const short* pB = wp + (size_t)kq * 128 + (size_t)r16 * 8;
    #define LD_B2(ni, s, ks) \
        (*(const short8*)(pB + ((((size_t)(head * 4 + (ni)) * 2 + (s)) * 32 + 4 * (ks)) * 128)))
    short8 Bh[2][4], Bl[2][4];
    #pragma unroll
    for (int ni = 0; ni < 4; ++ni) { Bh[0][ni] = LD_B2(ni, 0, 0); Bl[0][ni] = LD_B2(ni, 1, 0); }

    __syncthreads();   // nl_sh visible to fill

    #pragma unroll
    for (int q = 0; q < 4; ++q) {
        const int item = q * 512 + tid;
        const int row  = item >> 5;
        const int kc   = item & 31;
        const int grow = nl_sh[row];
        f32x4 v0 = {0.f, 0.f, 0.f, 0.f}, v1 = {0.f, 0.f, 0.f, 0.f};
        if (grow >= 0) {
            v0 = *(const f32x4*)(x + (size_t)grow * IN_DIM + kc * 8);
            v1 = *(const f32x4*)(x + (size_t)grow * IN_DIM + kc * 8 + 4);
        }
        unsigned hi[4], lo[4];
        bf16_split2(v0.x, v0.y, hi[0], lo[0]);
        bf16_split2(v0.z, v0.w, hi[1], lo[1]);
        bf16_split2(v1.x, v1.y, hi[2], lo[2]);
        bf16_split2(v1.z, v1.w, hi[3], lo[3]);
        const int mi  = row >> 4, rr = row & 15;
        const int swz = rr ^ (kc & 15);
        uint4 vh = make_uint4(hi[0], hi[1], hi[2], hi[3]);
        uint4 vl = make_uint4(lo[0], lo[1], lo[2], lo[3]);
        *(uint4*)((char*)As + ((((mi * 2 + 0) * 32 + kc) * 16 + swz) * 16)) = vh;
        *(uint4*)((char*)As + ((((mi * 2 + 1) * 32 + kc) * 16 + swz) * 16)) = vl;
    }
    __syncthreads();

    f32x4 acc[4][4] = {};

    #define LD_A2(mi, s, ks) \
        (*(const short8*)((const char*)As + \
            (((((mi) * 2 + (s)) * 32 + (4 * (ks) + kq)) * 16 + \
              (r16 ^ ((4 * ((ks) & 3) + kq)))) * 16)))

    short8 Ah[2][4], Al[2][4];
    #pragma unroll
    for (int mi = 0; mi < 4; ++mi) { Ah[0][mi] = LD_A2(mi, 0, 0); Al[0][mi] = LD_A2(mi, 1, 0); }

    #pragma unroll
    for (int ks = 0; ks < 8; ++ks) {
        const int cur = ks & 1, nxt = cur ^ 1;
        if (ks < 7) {
            #pragma unroll
            for (int ni = 0; ni < 4; ++ni) {
                Bh[nxt][ni] = LD_B2(ni, 0, ks + 1);
                Bl[nxt][ni] = LD_B2(ni, 1, ks + 1);
            }
            #pragma unroll
            for (int mi = 0; mi < 4; ++mi) {
                Ah[nxt][mi] = LD_A2(mi, 0, ks + 1);
                Al[nxt][mi] = LD_A2(mi, 1, ks + 1);
            }
        }
        #pragma unroll
        for (int mi = 0; mi < 4; ++mi)
            #pragma unroll
            for (int ni = 0; ni < 4; ++ni) {
                acc[mi][ni] = __builtin_amdgcn_mfma_f32_16x16x32_bf16(
                    Ah[cur][mi], Bh[cur][ni], acc[mi][ni], 0, 0, 0);
                acc[mi][ni] = __builtin_amdgcn_mfma_f32_16x16x32_bf16(
                    Ah[cur][mi], Bl[cur][ni], acc[mi][ni], 0, 0, 0);
                acc[mi][ni] = __builtin_amdgcn_mfma_f32_16x16x32_bf16(
                    Al[cur][mi], Bh[cur][ni], acc[mi][ni], 0, 0, 0);
            }
    }
    #undef LD_A2
    #undef LD_B2

    // epilogue: permuted-layout float4 Wh stores for valid rows
    const int n0 = head * 64;
    float bias[4];
    #pragma unroll
    for (int ni = 0; ni < 4; ++ni) bias[ni] = b[n0 + ni * 16 + r16];

    #pragma unroll
    for (int mi = 0; mi < 4; ++mi) {
        #pragma unroll
        for (int reg = 0; reg < 4; ++reg) {
            const int rloc = mi * 16 + kq * 4 + reg;
            const int n    = nl_sh[rloc];
            if (n >= 0) {
                *(float4*)(Wh + (size_t)n * NCOL + n0 + r16 * 4) =
                    make_float4(acc[mi][0][reg] + bias[0],
                                acc[mi][1][reg] + bias[1],
                                acc[mi][2][reg] + bias[2],
                                acc[mi][3][reg] + bias[3]);
            }
        }
    }
}

// ---------------------------------------------------------------------------
// acc_t: iterate compact passing-edge list; w[8] from tbuf gather (~2K edges);
// wave-cooperative gather of permuted Wh[col]; atomicAdd out.
// ---------------------------------------------------------------------------
__global__ __launch_bounds__(256) void acc_t_kernel(
    const int* __restrict__ ei, const float* __restrict__ tbuf,
    const float* __restrict__ Wh, const float* __restrict__ coef,
    const int* __restrict__ elist, const int* __restrict__ ecount,
    float* __restrict__ out)
{
    __shared__ float cM[8], cC[8];
    if (threadIdx.x < 8)       cM[threadIdx.x]     = coef[threadIdx.x];
    else if (threadIdx.x < 16) cC[threadIdx.x - 8] = coef[threadIdx.x];
    __syncthreads();

    const int n    = *ecount;
    const int lane = threadIdx.x & 63;

    for (int i = blockIdx.x * 256 + threadIdx.x; ; i += gridDim.x * 256) {
        const bool has = i < n;
        if (!__any(has)) break;

        int row = 0, col = 0;
        float wgt[8];
        if (has) {
            const int e = elist[i];
            row = ei[e];
            col = ei[N_EDGES + e];
            const float4 t0 = *(const float4*)(tbuf + (size_t)e * 8);
            const float4 t1 = *(const float4*)(tbuf + (size_t)e * 8 + 4);
            const float t[8] = { t0.x, t0.y, t0.z, t0.w, t1.x, t1.y, t1.z, t1.w };
            #pragma unroll
            for (int h = 0; h < 8; ++h)
                wgt[h] = __expf(t[h] - cM[h]) * cC[h];
        }

        unsigned long long mask = __ballot(has);
        while (mask) {
            const int src = (int)__builtin_ctzll(mask);
            mask &= mask - 1;
            const int rb = __shfl(row, src);
            const int cb = __shfl(col, src);
            // permuted Wh row: element (h, o) at h*64 + (o&15)*4 + (o>>4); o == lane
            const float* wc = Wh + (size_t)cb * NCOL + (lane & 15) * 4 + (lane >> 4);
            float acc = 0.f;
            #pragma unroll
            for (int h = 0; h < 8; ++h)
                acc += __shfl(wgt[h], src) * wc[h * 64];
            atomicAdd(out + (size_t)rb * OUT_DIM + lane, acc);
        }
    }
}

// ---------------------------------------------------------------------------
// Fallback acc (no tbuf): r5-verified gather version.
// ---------------------------------------------------------------------------
__global__ __launch_bounds__(256) void acc_kernel(
    const int* __restrict__ ei, const float* __restrict__ s_src,
    const float* __restrict__ s_dst, const float* __restrict__ Wh,
    const float* __restrict__ coef, const int* __restrict__ elist,
    const int* __restrict__ ecount, float* __restrict__ out)
{
    __shared__ float cM[8], cC[8];
    if (threadIdx.x < 8)       cM[threadIdx.x]     = coef[threadIdx.x];
    else if (threadIdx.x < 16) cC[threadIdx.x - 8] = coef[threadIdx.x];
    __syncthreads();

    const int n    = *ecount;
    const int lane = threadIdx.x & 63;

    for (int i = blockIdx.x * 256 + threadIdx.x; ; i += gridDim.x * 256) {
        const bool has = i < n;
        if (!__any(has)) break;

        int row = 0, col = 0;
        float wgt[8];
        if (has) {
            const int e = elist[i];
            row = ei[e];
            col = ei[N_EDGES + e];
            const float4 s0 = *(const float4*)(s_src + row * 8);
            const float4 s1 = *(const float4*)(s_src + row * 8 + 4);
            const float4 d0 = *(const float4*)(s_dst + col * 8);
            const float4 d1 = *(const float4*)(s_dst + col * 8 + 4);
            float t[8] = { s0.x + d0.x, s0.y + d0.y, s0.z + d0.z, s0.w + d0.w,
                           s1.x + d1.x, s1.y + d1.y, s1.z + d1.z, s1.w + d1.w };
            #pragma unroll
            for (int h = 0; h < 8; ++h) {
                t[h] = t[h] > 0.f ? t[h] : 0.01f * t[h];
                wgt[h] = __expf(t[h] - cM[h]) * cC[h];
            }
        }

        unsigned long long mask = __ballot(has);
        while (mask) {
            const int src = (int)__builtin_ctzll(mask);
            mask &= mask - 1;
            const int rb = __shfl(row, src);
            const int cb = __shfl(col, src);
            const float* wc = Wh + (size_t)cb * NCOL + (lane & 15) * 4 + (lane >> 4);
            float acc = 0.f;
            #pragma unroll
            for (int h = 0; h < 8; ++h)
                acc += __shfl(wgt[h], src) * wc[h * 64];
            atomicAdd(out + (size_t)rb * OUT_DIM + lane, acc);
        }
    }
}

// ---------------------------------------------------------------------------
extern "C" void kernel_launch(void* const* d_in, const int* in_sizes, int n_in,
                              void* d_out, int out_size, void* d_ws, size_t ws_size,
                              hipStream_t stream)
{
    const float* x    = (const float*)d_in[0];
    const int*   ei   = (const int*)  d_in[1];
    const float* W    = (const float*)d_in[2];
    const float* b    = (const float*)d_in[3];
    const float* a    = (const float*)d_in[4];
    const float* gate = (const float*)d_in[5];
    float* out = (float*)d_out;

    // workspace (floats): Wh | s_src | s_dst | partial | coef | wp | elist |
    //                     colflag | ecount | ncount | nlist | tbuf  (~135 MB)
    float* ws      = (float*)d_ws;
    float* Wh      = ws;
    float* s_src   = Wh    + (size_t)N_NODES * NCOL;
    float* s_dst   = s_src + (size_t)N_NODES * HEADS;
    float* partial = s_dst + (size_t)N_NODES * HEADS;
    float* coef    = partial + (size_t)NBLK_RED * 16;
    short* wp      = (short*)(coef + 32);              // 512 KB, 16B-aligned
    int*   elist   = (int*)(wp + 262144);              // 800K ints
    int*   colflag = elist + N_EDGES;                  // 50K ints
    int*   ecount  = colflag + N_NODES;                // 1 int
    int*   ncount  = ecount + 1;                       // 1 int
    int*   nlist   = ncount + 1;                       // 50K ints
    float* tbuf    = (float*)(nlist + N_NODES);        // 25.6 MB (optional)

    const size_t base_bytes = (size_t)((char*)tbuf - (char*)ws);
    const size_t need_tbuf  = base_bytes + (size_t)N_EDGES * 8 * sizeof(float);
    const bool   use_tbuf   = ws_size >= need_tbuf;

    hipMemsetAsync(d_out, 0, (size_t)N_NODES * OUT_DIM * sizeof(float), stream);
    hipMemsetAsync(colflag, 0, (size_t)(N_NODES + 2) * sizeof(int), stream);

    packw_kernel<<<32, 256, 0, stream>>>(W, wp);

    gemm_kernel<<<(N_NODES + 63) / 64, 512, 0, stream>>>(x, wp, b, a, s_src, s_dst);

    edge_score_kernel<<<NBLK_RED, 256, 0, stream>>>(
        ei, s_src, s_dst, use_tbuf ? tbuf : nullptr, partial);

    finalize_kernel<<<1, 256, 0, stream>>>(partial, gate, coef, NBLK_RED);

    if (use_tbuf)
        mark_t_kernel<<<(N_EDGES + 255) / 256, 256, 0, stream>>>(
            ei, tbuf, coef, elist, colflag, ecount, ncount, nlist);
    else
        mark_kernel<<<(N_EDGES + 255) / 256, 256, 0, stream>>>(
            ei, s_src, s_dst, coef, elist, colflag, ecount, ncount, nlist);

    whrows_kernel<<<(N_NODES + 63) / 64, 512, 0, stream>>>(
        x, wp, b, nlist, ncount, Wh);

    if (use_tbuf)
        acc_t_kernel<<<256, 256, 0, stream>>>(
            ei, tbuf, Wh, coef, elist, ecount, out);
    else
        acc_kernel<<<256, 256, 0, stream>>>(
            ei, s_src, s_dst, Wh, coef, elist, ecount, out);
}

// Round 7
// 236.154 us; speedup vs baseline: 1.7033x; 1.7033x over previous
//
#include <hip/hip_runtime.h>
#include <hip/hip_bf16.h>

// EGA layer (GAT-like, GLOBAL per-head softmax over edges) on MI355X.
// Pipeline:
//   packw -> MFMA split-GEMM (scores ONLY, no Wh store) -> edge score pass
//   (writes t-buffer + online (m,l) partials) -> finalize -> mark_flags
//   (coalesced threshold pass, PLAIN colflag stores, ZERO atomics) ->
//   compact_nodes (196 block-level atomics) -> whrows (MFMA bf16x3 Wh
//   recompute for marked cols only) -> acc_st (stream tbuf, inline re-test,
//   scatter passing edges).
// Evidence r5/r6: per-edge single-address compaction atomics (ecount/ncount
// same cache line + colflag atomicExch) cost ~130us -- gather-mark (141us)
// and fully-coalesced mark_t (138us) were equal, while the atomic-free r2
// scatter_t on the same stream was fast. This round removes them.
// Worst case (flat scores) degrades to one extra full MFMA GEMM: bounded.

#define N_NODES 50000
#define N_EDGES 800000
#define IN_DIM  256
#define OUT_DIM 64
#define HEADS   8
#define NCOL    (HEADS * OUT_DIM)   // 512
#define NBLK_RED 2048               // partial-reduction blocks for edge softmax
#define LN_W_EPS (-20.72326584f)    // ln(1e-9) skip threshold

typedef __attribute__((ext_vector_type(8))) short short8;   // 8 x bf16 (4 VGPRs)
typedef __attribute__((ext_vector_type(4))) float f32x4;

// RNE bf16 hi + trunc bf16 lo split of 2 floats -> packed u32s (lane-order j, j+1)
__device__ __forceinline__ void bf16_split2(float x0, float x1,
                                            unsigned& hi, unsigned& lo)
{
    unsigned u0 = __float_as_uint(x0), u1 = __float_as_uint(x1);
    unsigned r0 = u0 + 0x7FFFu + ((u0 >> 16) & 1u);   // RNE to bf16
    unsigned r1 = u1 + 0x7FFFu + ((u1 >> 16) & 1u);
    float h0 = __uint_as_float(r0 & 0xFFFF0000u);
    float h1 = __uint_as_float(r1 & 0xFFFF0000u);
    hi = (r0 >> 16) | (r1 & 0xFFFF0000u);
    unsigned l0 = __float_as_uint(x0 - h0);           // residual, trunc to bf16
    unsigned l1 = __float_as_uint(x1 - h1);
    lo = (l0 >> 16) | (l1 & 0xFFFF0000u);
}

// ---------------------------------------------------------------------------
// Pack W (fp32 [8][256][64]) into B-fragment layout, bf16 hi/lo.
// B fragment for mfma_16x16x32: lane l -> col=l&15, k=(l>>4)*8+j  => a wave's
// fragment read is 1KB contiguous. Total 512 KB, stays L2-resident.
// ---------------------------------------------------------------------------
__global__ __launch_bounds__(256) void packw_kernel(
    const float* __restrict__ W, short* __restrict__ wp)
{
    const int ct = blockIdx.x;            // 0..31
    const int h  = ct >> 2;               // head (4 col-tiles per head)
    #pragma unroll
    for (int it = 0; it < 2; ++it) {
        const int i  = threadIdx.x + it * 256;   // 512 items: (k8, c)
        const int k8 = i >> 4;
        const int c  = i & 15;
        const int o  = (ct & 3) * 16 + c;
        const float* src = W + (size_t)h * IN_DIM * OUT_DIM
                             + (size_t)k8 * 8 * OUT_DIM + o;
        unsigned hi[4], lo[4];
        #pragma unroll
        for (int p = 0; p < 4; ++p) {
            float x0 = src[(2 * p) * OUT_DIM];
            float x1 = src[(2 * p + 1) * OUT_DIM];
            bf16_split2(x0, x1, hi[p], lo[p]);
        }
        uint4 vh = make_uint4(hi[0], hi[1], hi[2], hi[3]);
        uint4 vl = make_uint4(lo[0], lo[1], lo[2], lo[3]);
        *(uint4*)(wp + (((size_t)(ct * 2 + 0) * 32 + k8) * 128) + c * 8) = vh;
        *(uint4*)(wp + (((size_t)(ct * 2 + 1) * 32 + k8) * 128) + c * 8) = vl;
    }
}

// ---------------------------------------------------------------------------
// MFMA GEMM, SCORES ONLY. 512 threads = 8 waves; wave == head; one 64-row
// x-panel staged ONCE per block (serves all 8 heads), bf16 hi/lo, XOR-swizzle.
// __launch_bounds__(512,2): 256-reg budget AND 2 blocks/CU = 4 waves/SIMD.
// Scores staged in LDS, float4 stores.
// ---------------------------------------------------------------------------
__global__ __launch_bounds__(512, 2) void gemm_kernel(
    const float* __restrict__ x, const short* __restrict__ wp,
    const float* __restrict__ b, const float* __restrict__ a,
    float* __restrict__ s_src, float* __restrict__ s_dst)
{
    // [mi(4)][s(2)][k8(32)][r(16)][j(8)] halfs, 16B chunk index XOR-swizzled
    __shared__ __align__(16) short As[32768];        // 64 KB
    __shared__ __align__(16) float s_tmp[2][64][8];  // 4 KB score staging

    const int row0 = blockIdx.x * 64;
    const int tid  = threadIdx.x;
    const int lane = tid & 63;
    const int head = tid >> 6;            // wave == head 0..7
    const int r16  = lane & 15;
    const int kq   = lane >> 4;

    // ---- prefetch B[ks=0] before the fill: L2 latency hides under fill ----
    const short* pB = wp + (size_t)kq * 128 + (size_t)r16 * 8;
    #define LD_B(ni, s, ks) \
        (*(const short8*)(pB + ((((size_t)(head * 4 + (ni)) * 2 + (s)) * 32 + 4 * (ks)) * 128)))
    short8 Bh[2][4], Bl[2][4];
    #pragma unroll
    for (int ni = 0; ni < 4; ++ni) { Bh[0][ni] = LD_B(ni, 0, 0); Bl[0][ni] = LD_B(ni, 1, 0); }

    // ---- fill LDS: x panel -> bf16 hi/lo fragment layout (once per block) ----
    #pragma unroll
    for (int q = 0; q < 4; ++q) {
        const int item = q * 512 + tid;           // 2048 items: (row, kc)
        const int row  = item >> 5;               // 0..63
        const int kc   = item & 31;               // K-chunk of 8
        const int grow = row0 + row;
        f32x4 v0 = {0.f, 0.f, 0.f, 0.f}, v1 = {0.f, 0.f, 0.f, 0.f};
        if (grow < N_NODES) {
            v0 = *(const f32x4*)(x + (size_t)grow * IN_DIM + kc * 8);
            v1 = *(const f32x4*)(x + (size_t)grow * IN_DIM + kc * 8 + 4);
        }
        unsigned hi[4], lo[4];
        bf16_split2(v0.x, v0.y, hi[0], lo[0]);
        bf16_split2(v0.z, v0.w, hi[1], lo[1]);
        bf16_split2(v1.x, v1.y, hi[2], lo[2]);
        bf16_split2(v1.z, v1.w, hi[3], lo[3]);
        const int mi  = row >> 4, rr = row & 15;
        const int swz = rr ^ (kc & 15);
        uint4 vh = make_uint4(hi[0], hi[1], hi[2], hi[3]);
        uint4 vl = make_uint4(lo[0], lo[1], lo[2], lo[3]);
        *(uint4*)((char*)As + ((((mi * 2 + 0) * 32 + kc) * 16 + swz) * 16)) = vh;
        *(uint4*)((char*)As + ((((mi * 2 + 1) * 32 + kc) * 16 + swz) * 16)) = vl;
    }
    __syncthreads();

    // ---- K-loop (verified r1/r2 structure) ----
    f32x4 acc[4][4] = {};

    #define LD_A(mi, s, ks) \
        (*(const short8*)((const char*)As + \
            (((((mi) * 2 + (s)) * 32 + (4 * (ks) + kq)) * 16 + \
              (r16 ^ ((4 * ((ks) & 3) + kq)))) * 16)))

    short8 Ah[2][4], Al[2][4];
    #pragma unroll
    for (int mi = 0; mi < 4; ++mi) { Ah[0][mi] = LD_A(mi, 0, 0); Al[0][mi] = LD_A(mi, 1, 0); }

    #pragma unroll
    for (int ks = 0; ks < 8; ++ks) {
        const int cur = ks & 1, nxt = cur ^ 1;
        if (ks < 7) {
            #pragma unroll
            for (int ni = 0; ni < 4; ++ni) {
                Bh[nxt][ni] = LD_B(ni, 0, ks + 1);
                Bl[nxt][ni] = LD_B(ni, 1, ks + 1);
            }
            #pragma unroll
            for (int mi = 0; mi < 4; ++mi) {
                Ah[nxt][mi] = LD_A(mi, 0, ks + 1);
                Al[nxt][mi] = LD_A(mi, 1, ks + 1);
            }
        }
        #pragma unroll
        for (int mi = 0; mi < 4; ++mi)
            #pragma unroll
            for (int ni = 0; ni < 4; ++ni) {
                acc[mi][ni] = __builtin_amdgcn_mfma_f32_16x16x32_bf16(
                    Ah[cur][mi], Bh[cur][ni], acc[mi][ni], 0, 0, 0);
                acc[mi][ni] = __builtin_amdgcn_mfma_f32_16x16x32_bf16(
                    Ah[cur][mi], Bl[cur][ni], acc[mi][ni], 0, 0, 0);
                acc[mi][ni] = __builtin_amdgcn_mfma_f32_16x16x32_bf16(
                    Al[cur][mi], Bh[cur][ni], acc[mi][ni], 0, 0, 0);
            }
    }
    #undef LD_A
    #undef LD_B

    // ---- epilogue: fused score dot-products only (no Wh store) ----
    // C layout (verified): col = lane&15, row = (lane>>4)*4 + reg
    const int n0 = head * 64;
    float bias[4], avs[4], avd[4];
    #pragma unroll
    for (int ni = 0; ni < 4; ++ni) {
        bias[ni] = b[n0 + ni * 16 + r16];
        avs[ni]  = a[head * 128 + ni * 16 + r16];
        avd[ni]  = a[head * 128 + 64 + ni * 16 + r16];
    }
    #pragma unroll
    for (int mi = 0; mi < 4; ++mi) {
        #pragma unroll
        for (int reg = 0; reg < 4; ++reg) {
            float ps = 0.f, pd = 0.f;
            #pragma unroll
            for (int ni = 0; ni < 4; ++ni) {
                const float v = acc[mi][ni][reg] + bias[ni];
                ps += v * avs[ni];
                pd += v * avd[ni];
            }
            ps += __shfl_xor(ps, 1); pd += __shfl_xor(pd, 1);
            ps += __shfl_xor(ps, 2); pd += __shfl_xor(pd, 2);
            ps += __shfl_xor(ps, 4); pd += __shfl_xor(pd, 4);
            ps += __shfl_xor(ps, 8); pd += __shfl_xor(pd, 8);
            if (r16 == 0) {
                const int rloc = mi * 16 + kq * 4 + reg;
                s_tmp[0][rloc][head] = ps;
                s_tmp[1][rloc][head] = pd;
            }
        }
    }
    __syncthreads();
    if (tid < 256) {
        const int r   = tid & 63;
        const int sel = tid >> 6;            // 0..3: src-lo, src-hi, dst-lo, dst-hi
        const int gr  = row0 + r;
        if (gr < N_NODES) {
            float* dst = (sel < 2) ? s_src : s_dst;
            *(float4*)(dst + (size_t)gr * 8 + (sel & 1) * 4) =
                *(const float4*)&s_tmp[sel >> 1][r][(sel & 1) * 4];
        }
    }
}

// ---------------------------------------------------------------------------
// Edge score pass: lane-pair split (even lane: heads 0-3, odd: heads 4-7).
// Per edge-pair: ONE float4 gather per table per lane + half the per-lane
// online-softmax VALU. Writes t[8] coalesced to tbuf (if non-null) and
// per-block online (m,l) partials.
// ---------------------------------------------------------------------------
__global__ __launch_bounds__(256) void edge_score_kernel(
    const int* __restrict__ ei, const float* __restrict__ s_src,
    const float* __restrict__ s_dst, float* __restrict__ tbuf,
    float* __restrict__ partial)
{
    const int tid  = threadIdx.x;
    const int half = tid & 1;            // heads half*4 .. half*4+3

    float m[4], l[4];
    #pragma unroll
    for (int i = 0; i < 4; ++i) { m[i] = -1e30f; l[i] = 0.f; }

    for (int p = blockIdx.x * 128 + (tid >> 1); p < N_EDGES; p += gridDim.x * 128) {
        const int row = ei[p];
        const int col = ei[N_EDGES + p];
        const f32x4 s = *(const f32x4*)(s_src + row * 8 + half * 4);
        const f32x4 d = *(const f32x4*)(s_dst + col * 8 + half * 4);
        float t[4];
        #pragma unroll
        for (int i = 0; i < 4; ++i) {
            float v = s[i] + d[i];
            t[i] = v > 0.f ? v : 0.01f * v;       // leaky_relu 0.01
        }
        if (tbuf)
            *(float4*)(tbuf + (size_t)p * 8 + half * 4) =
                make_float4(t[0], t[1], t[2], t[3]);
        #pragma unroll
        for (int i = 0; i < 4; ++i) {
            const float mn = fmaxf(m[i], t[i]);
            l[i] = l[i] * __expf(m[i] - mn) + __expf(t[i] - mn);
            m[i] = mn;
        }
    }

    // block reduce; parity-preserving strides keep head mapping intact
    __shared__ float red[8][256];
    #pragma unroll
    for (int i = 0; i < 4; ++i) { red[i][tid] = m[i]; red[4 + i][tid] = l[i]; }
    __syncthreads();
    for (int s = 128; s >= 2; s >>= 1) {
        if (tid < s) {
            #pragma unroll
            for (int i = 0; i < 4; ++i) {
                const float mo = red[i][tid + s], lo = red[4 + i][tid + s];
                const float mm = red[i][tid],     ll = red[4 + i][tid];
                const float mn = fmaxf(mm, mo);
                red[4 + i][tid] = ll * __expf(mm - mn) + lo * __expf(mo - mn);
                red[i][tid]     = mn;
            }
        }
        __syncthreads();
    }
    if (tid < 2) {
        #pragma unroll
        for (int i = 0; i < 4; ++i) {
            partial[blockIdx.x * 16 + tid * 4 + i]     = red[i][tid];
            partial[blockIdx.x * 16 + 8 + tid * 4 + i] = red[4 + i][tid];
        }
    }
}

// ---------------------------------------------------------------------------
// Merge partials. coef[h]=M_h, coef[8+h]=g_h/L_h, coef[16+h]=skip cutoff.
// ---------------------------------------------------------------------------
__global__ __launch_bounds__(256) void finalize_kernel(
    const float* __restrict__ partial, const float* __restrict__ gate,
    float* __restrict__ coef, int nblk)
{
    const int t = threadIdx.x;
    const int h = t & 7;
    const int j = t >> 3;                 // 0..31
    float m = -1e30f, l = 0.f;
    for (int bk = j; bk < nblk; bk += 32) {
        const float mb = partial[bk * 16 + h];
        const float lb = partial[bk * 16 + 8 + h];
        const float mn = fmaxf(m, mb);
        l = l * __expf(m - mn) + lb * __expf(mb - mn);
        m = mn;
    }
    __shared__ float rm[256], rl[256];
    rm[t] = m; rl[t] = l;
    __syncthreads();
    for (int s = 128; s >= 8; s >>= 1) {
        if (t < s) {
            const float mo = rm[t + s], lo = rl[t + s];
            const float mn = fmaxf(rm[t], mo);
            rl[t] = rl[t] * __expf(rm[t] - mn) + lo * __expf(mo - mn);
            rm[t] = mn;
        }
        __syncthreads();
    }
    if (t < 8) {
        float gm = gate[0];
        for (int i = 1; i < 8; ++i) gm = fmaxf(gm, gate[i]);
        float gs = 0.f;
        for (int i = 0; i < 8; ++i) gs += __expf(gate[i] - gm);
        const float g = __expf(gate[t] - gm) / gs;
        const float C = g / rl[t];
        coef[t]      = rm[t];
        coef[8 + t]  = C;
        coef[16 + t] = rm[t] + LN_W_EPS - __logf(C);   // t >= cut  <=>  w >= eps
    }
}

// ---------------------------------------------------------------------------
// mark_flags: coalesced threshold pass over tbuf with ZERO atomics.
// Passing lanes plain-store colflag[col]=1 (benign race: all writers store 1).
// r5/r6 evidence: the per-edge compaction atomics cost ~130us; this pass
// keeps only the streaming.
// ---------------------------------------------------------------------------
__global__ __launch_bounds__(256) void mark_flags_kernel(
    const int* __restrict__ ei, const float* __restrict__ tbuf,
    const float* __restrict__ coef, int* __restrict__ colflag)
{
    __shared__ float cCut[8];
    if (threadIdx.x < 8) cCut[threadIdx.x] = coef[16 + threadIdx.x];
    __syncthreads();

    const int e = blockIdx.x * 256 + threadIdx.x;
    if (e >= N_EDGES) return;
    const float4 t0 = *(const float4*)(tbuf + (size_t)e * 8);
    const float4 t1 = *(const float4*)(tbuf + (size_t)e * 8 + 4);
    const bool pass =
        (t0.x >= cCut[0]) | (t0.y >= cCut[1]) |
        (t0.z >= cCut[2]) | (t0.w >= cCut[3]) |
        (t1.x >= cCut[4]) | (t1.y >= cCut[5]) |
        (t1.z >= cCut[6]) | (t1.w >= cCut[7]);
    if (pass)
        colflag[ei[N_EDGES + e]] = 1;     // plain store, no atomic
}

// ---------------------------------------------------------------------------
// compact_nodes: block-level ballot compaction of colflag into nlist.
// ONE atomicAdd per block (196 total) -- negligible contention.
// ---------------------------------------------------------------------------
__global__ __launch_bounds__(256) void compact_nodes_kernel(
    const int* __restrict__ colflag, int* __restrict__ ncount,
    int* __restrict__ nlist)
{
    const int n    = blockIdx.x * 256 + threadIdx.x;
    const int lane = threadIdx.x & 63;
    const int w    = threadIdx.x >> 6;
    const bool f   = (n < N_NODES) && (colflag[n] != 0);
    const unsigned long long mask = __ballot(f);

    __shared__ int wcnt[4];
    __shared__ int bbase;
    if (lane == 0) wcnt[w] = (int)__popcll(mask);
    __syncthreads();
    if (threadIdx.x == 0) {
        const int tot = wcnt[0] + wcnt[1] + wcnt[2] + wcnt[3];
        bbase = tot ? atomicAdd(ncount, tot) : 0;
    }
    __syncthreads();
    if (f) {
        int wbase = bbase;
        for (int i = 0; i < w; ++i) wbase += wcnt[i];
        const int rank = (int)__popcll(mask & ((1ULL << lane) - 1ULL));
        nlist[wbase + rank] = n;
    }
}

// ---------------------------------------------------------------------------
// Fallback mark (no tbuf space): r5-verified gather version (builds elist,
// colflag, nlist itself).
// ---------------------------------------------------------------------------
__global__ __launch_bounds__(256) void mark_kernel(
    const int* __restrict__ ei, const float* __restrict__ s_src,
    const float* __restrict__ s_dst, const float* __restrict__ coef,
    int* __restrict__ elist, int* __restrict__ colflag,
    int* __restrict__ ecount, int* __restrict__ ncount, int* __restrict__ nlist)
{
    __shared__ float cCut[8];
    if (threadIdx.x < 8) cCut[threadIdx.x] = coef[16 + threadIdx.x];
    __syncthreads();

    const int e = blockIdx.x * 256 + threadIdx.x;
    bool pass = false;
    int col = 0;
    if (e < N_EDGES) {
        const int row = ei[e];
        col = ei[N_EDGES + e];
        const float4 s0 = *(const float4*)(s_src + row * 8);
        const float4 s1 = *(const float4*)(s_src + row * 8 + 4);
        const float4 d0 = *(const float4*)(s_dst + col * 8);
        const float4 d1 = *(const float4*)(s_dst + col * 8 + 4);
        float t[8] = { s0.x + d0.x, s0.y + d0.y, s0.z + d0.z, s0.w + d0.w,
                       s1.x + d1.x, s1.y + d1.y, s1.z + d1.z, s1.w + d1.w };
        #pragma unroll
        for (int h = 0; h < 8; ++h) {
            t[h] = t[h] > 0.f ? t[h] : 0.01f * t[h];
            pass |= (t[h] >= cCut[h]);
        }
    }

    const unsigned long long mask = __ballot(pass);
    if (mask) {
        const int lane   = threadIdx.x & 63;
        const int leader = (int)__builtin_ctzll(mask);
        int base = 0;
        if (lane == leader) base = atomicAdd(ecount, (int)__popcll(mask));
        base = __shfl(base, leader);
        if (pass) {
            const int rank = (int)__popcll(mask & ((1ULL << lane) - 1ULL));
            elist[base + rank] = e;
            if (atomicExch(&colflag[col], 1) == 0) {
                const int ni = atomicAdd(ncount, 1);
                nlist[ni] = col;
            }
        }
    }
}

// ---------------------------------------------------------------------------
// Wh recompute for marked cols only -- SAME verified MFMA bf16x3 block as the
// score GEMM, row indices indirected through the compacted nlist. Early exit
// past ncount. Wh stored PERMUTED (element (h,o) at h*64 + (o&15)*4 + (o>>4)).
// ---------------------------------------------------------------------------
__global__ __launch_bounds__(512, 2) void whrows_kernel(
    const float* __restrict__ x, const short* __restrict__ wp,
    const float* __restrict__ b, const int* __restrict__ nlist,
    const int* __restrict__ ncount, float* __restrict__ Wh)
{
    __shared__ __align__(16) short As[32768];   // 64 KB
    __shared__ int nl_sh[64];

    const int nc   = *ncount;
    const int row0 = blockIdx.x * 64;
    if (row0 >= nc) return;

    const int tid  = threadIdx.x;
    const int lane = tid & 63;
    const int head = tid >> 6;            // wave == head 0..7
    const int r16  = lane & 15;
    const int kq   = lane >> 4;

    if (tid < 64) {
        const int idx = row0 + tid;
        nl_sh[tid] = (idx < nc) ? nlist[idx] : -1;
    }

    const short* pB = wp + (size_t)kq * 128 + (size_t)r16 * 8;
    #define LD_B2(ni, s, ks) \
        (*(const short8*)(pB + ((((size_t)(head * 4 + (ni)) * 2 + (s)) * 32 + 4 * (ks)) * 128)))
    short8 Bh[2][4], Bl[2][4];
    #pragma unroll
    for (int ni = 0; ni < 4; ++ni) { Bh[0][ni] = LD_B2(ni, 0, 0); Bl[0][ni] = LD_B2(ni, 1, 0); }

    __syncthreads();   // nl_sh visible to fill

    #pragma unroll
    for (int q = 0; q < 4; ++q) {
        const int item = q * 512 + tid;
        const int row  = item >> 5;
        const int kc   = item & 31;
        const int grow = nl_sh[row];
        f32x4 v0 = {0.f, 0.f, 0.f, 0.f}, v1 = {0.f, 0.f, 0.f, 0.f};
        if (grow >= 0) {
            v0 = *(const f32x4*)(x + (size_t)grow * IN_DIM + kc * 8);
            v1 = *(const f32x4*)(x + (size_t)grow * IN_DIM + kc * 8 + 4);
        }
        unsigned hi[4], lo[4];
        bf16_split2(v0.x, v0.y, hi[0], lo[0]);
        bf16_split2(v0.z, v0.w, hi[1], lo[1]);
        bf16_split2(v1.x, v1.y, hi[2], lo[2]);
        bf16_split2(v1.z, v1.w, hi[3], lo[3]);
        const int mi  = row >> 4, rr = row & 15;
        const int swz = rr ^ (kc & 15);
        uint4 vh = make_uint4(hi[0], hi[1], hi[2], hi[3]);
        uint4 vl = make_uint4(lo[0], lo[1], lo[2], lo[3]);
        *(uint4*)((char*)As + ((((mi * 2 + 0) * 32 + kc) * 16 + swz) * 16)) = vh;
        *(uint4*)((char*)As + ((((mi * 2 + 1) * 32 + kc) * 16 + swz) * 16)) = vl;
    }
    __syncthreads();

    f32x4 acc[4][4] = {};

    #define LD_A2(mi, s, ks) \
        (*(const short8*)((const char*)As + \
            (((((mi) * 2 + (s)) * 32 + (4 * (ks) + kq)) * 16 + \
              (r16 ^ ((4 * ((ks) & 3) + kq)))) * 16)))

    short8 Ah[2][4], Al[2][4];
    #pragma unroll
    for (int mi = 0; mi < 4; ++mi) { Ah[0][mi] = LD_A2(mi, 0, 0); Al[0][mi] = LD_A2(mi, 1, 0); }

    #pragma unroll
    for (int ks = 0; ks < 8; ++ks) {
        const int cur = ks & 1, nxt = cur ^ 1;
        if (ks < 7) {
            #pragma unroll
            for (int ni = 0; ni < 4; ++ni) {
                Bh[nxt][ni] = LD_B2(ni, 0, ks + 1);
                Bl[nxt][ni] = LD_B2(ni, 1, ks + 1);
            }
            #pragma unroll
            for (int mi = 0; mi < 4; ++mi) {
                Ah[nxt][mi] = LD_A2(mi, 0, ks + 1);
                Al[nxt][mi] = LD_A2(mi, 1, ks + 1);
            }
        }
        #pragma unroll
        for (int mi = 0; mi < 4; ++mi)
            #pragma unroll
            for (int ni = 0; ni < 4; ++ni) {
                acc[mi][ni] = __builtin_amdgcn_mfma_f32_16x16x32_bf16(
                    Ah[cur][mi], Bh[cur][ni], acc[mi][ni], 0, 0, 0);
                acc[mi][ni] = __builtin_amdgcn_mfma_f32_16x16x32_bf16(
                    Ah[cur][mi], Bl[cur][ni], acc[mi][ni], 0, 0, 0);
                acc[mi][ni] = __builtin_amdgcn_mfma_f32_16x16x32_bf16(
                    Al[cur][mi], Bh[cur][ni], acc[mi][ni], 0, 0, 0);
            }
    }
    #undef LD_A2
    #undef LD_B2

    // epilogue: permuted-layout float4 Wh stores for valid rows
    const int n0 = head * 64;
    float bias[4];
    #pragma unroll
    for (int ni = 0; ni < 4; ++ni) bias[ni] = b[n0 + ni * 16 + r16];

    #pragma unroll
    for (int mi = 0; mi < 4; ++mi) {
        #pragma unroll
        for (int reg = 0; reg < 4; ++reg) {
            const int rloc = mi * 16 + kq * 4 + reg;
            const int n    = nl_sh[rloc];
            if (n >= 0) {
                *(float4*)(Wh + (size_t)n * NCOL + n0 + r16 * 4) =
                    make_float4(acc[mi][0][reg] + bias[0],
                                acc[mi][1][reg] + bias[1],
                                acc[mi][2][reg] + bias[2],
                                acc[mi][3][reg] + bias[3]);
            }
        }
    }
}

// ---------------------------------------------------------------------------
// acc_st: r2-proven scatter pattern. Stream tbuf coalesced, re-test the cut
// inline, load ei only for passing lanes, wave-cooperative gather of permuted
// Wh[col], atomicAdd out (scattered addresses, uncontended). No elist.
// ---------------------------------------------------------------------------
__global__ __launch_bounds__(256) void acc_st_kernel(
    const int* __restrict__ ei, const float* __restrict__ tbuf,
    const float* __restrict__ Wh, const float* __restrict__ coef,
    float* __restrict__ out)
{
    __shared__ float cM[8], cC[8], cCut[8];
    if (threadIdx.x < 8)       cM[threadIdx.x]        = coef[threadIdx.x];
    else if (threadIdx.x < 16) cC[threadIdx.x - 8]    = coef[threadIdx.x];
    else if (threadIdx.x < 24) cCut[threadIdx.x - 16] = coef[threadIdx.x];
    __syncthreads();

    const int lane = threadIdx.x & 63;
    const int e    = blockIdx.x * 256 + threadIdx.x;

    bool pass = false;
    float t[8];
    if (e < N_EDGES) {
        const float4 t0 = *(const float4*)(tbuf + (size_t)e * 8);
        const float4 t1 = *(const float4*)(tbuf + (size_t)e * 8 + 4);
        t[0] = t0.x; t[1] = t0.y; t[2] = t0.z; t[3] = t0.w;
        t[4] = t1.x; t[5] = t1.y; t[6] = t1.z; t[7] = t1.w;
        #pragma unroll
        for (int h = 0; h < 8; ++h) pass |= (t[h] >= cCut[h]);
    }

    int row = 0, col = 0;
    float wgt[8];
    if (pass) {
        row = ei[e];
        col = ei[N_EDGES + e];
        #pragma unroll
        for (int h = 0; h < 8; ++h)
            wgt[h] = __expf(t[h] - cM[h]) * cC[h];
    }

    unsigned long long mask = __ballot(pass);
    while (mask) {
        const int src = (int)__builtin_ctzll(mask);
        mask &= mask - 1;
        const int rb = __shfl(row, src);
        const int cb = __shfl(col, src);
        // permuted Wh row: element (h, o) at h*64 + (o&15)*4 + (o>>4); o == lane
        const float* wc = Wh + (size_t)cb * NCOL + (lane & 15) * 4 + (lane >> 4);
        float acc = 0.f;
        #pragma unroll
        for (int h = 0; h < 8; ++h)
            acc += __shfl(wgt[h], src) * wc[h * 64];
        atomicAdd(out + (size_t)rb * OUT_DIM + lane, acc);
    }
}

// ---------------------------------------------------------------------------
// Fallback acc (no tbuf): r5-verified gather version over elist.
// ---------------------------------------------------------------------------
__global__ __launch_bounds__(256) void acc_kernel(
    const int* __restrict__ ei, const float* __restrict__ s_src,
    const float* __restrict__ s_dst, const float* __restrict__ Wh,
    const float* __restrict__ coef, const int* __restrict__ elist,
    const int* __restrict__ ecount, float* __restrict__ out)
{
    __shared__ float cM[8], cC[8];
    if (threadIdx.x < 8)       cM[threadIdx.x]     = coef[threadIdx.x];
    else if (threadIdx.x < 16) cC[threadIdx.x - 8] = coef[threadIdx.x];
    __syncthreads();

    const int n    = *ecount;
    const int lane = threadIdx.x & 63;

    for (int i = blockIdx.x * 256 + threadIdx.x; ; i += gridDim.x * 256) {
        const bool has = i < n;
        if (!__any(has)) break;

        int row = 0, col = 0;
        float wgt[8];
        if (has) {
            const int e = elist[i];
            row = ei[e];
            col = ei[N_EDGES + e];
            const float4 s0 = *(const float4*)(s_src + row * 8);
            const float4 s1 = *(const float4*)(s_src + row * 8 + 4);
            const float4 d0 = *(const float4*)(s_dst + col * 8);
            const float4 d1 = *(const float4*)(s_dst + col * 8 + 4);
            float t[8] = { s0.x + d0.x, s0.y + d0.y, s0.z + d0.z, s0.w + d0.w,
                           s1.x + d1.x, s1.y + d1.y, s1.z + d1.z, s1.w + d1.w };
            #pragma unroll
            for (int h = 0; h < 8; ++h) {
                t[h] = t[h] > 0.f ? t[h] : 0.01f * t[h];
                wgt[h] = __expf(t[h] - cM[h]) * cC[h];
            }
        }

        unsigned long long mask = __ballot(has);
        while (mask) {
            const int src = (int)__builtin_ctzll(mask);
            mask &= mask - 1;
            const int rb = __shfl(row, src);
            const int cb = __shfl(col, src);
            const float* wc = Wh + (size_t)cb * NCOL + (lane & 15) * 4 + (lane >> 4);
            float acc = 0.f;
            #pragma unroll
            for (int h = 0; h < 8; ++h)
                acc += __shfl(wgt[h], src) * wc[h * 64];
            atomicAdd(out + (size_t)rb * OUT_DIM + lane, acc);
        }
    }
}

// ---------------------------------------------------------------------------
extern "C" void kernel_launch(void* const* d_in, const int* in_sizes, int n_in,
                              void* d_out, int out_size, void* d_ws, size_t ws_size,
                              hipStream_t stream)
{
    const float* x    = (const float*)d_in[0];
    const int*   ei   = (const int*)  d_in[1];
    const float* W    = (const float*)d_in[2];
    const float* b    = (const float*)d_in[3];
    const float* a    = (const float*)d_in[4];
    const float* gate = (const float*)d_in[5];
    float* out = (float*)d_out;

    // workspace (floats): Wh | s_src | s_dst | partial | coef | wp | elist |
    //                     colflag | ecount | ncount | nlist | tbuf  (~135 MB)
    float* ws      = (float*)d_ws;
    float* Wh      = ws;
    float* s_src   = Wh    + (size_t)N_NODES * NCOL;
    float* s_dst   = s_src + (size_t)N_NODES * HEADS;
    float* partial = s_dst + (size_t)N_NODES * HEADS;
    float* coef    = partial + (size_t)NBLK_RED * 16;
    short* wp      = (short*)(coef + 32);              // 512 KB, 16B-aligned
    int*   elist   = (int*)(wp + 262144);              // 800K ints (fallback only)
    int*   colflag = elist + N_EDGES;                  // 50K ints
    int*   ecount  = colflag + N_NODES;                // 1 int
    int*   ncount  = ecount + 1;                       // 1 int
    int*   nlist   = ncount + 1;                       // 50K ints
    float* tbuf    = (float*)(nlist + N_NODES);        // 25.6 MB (optional)

    const size_t base_bytes = (size_t)((char*)tbuf - (char*)ws);
    const size_t need_tbuf  = base_bytes + (size_t)N_EDGES * 8 * sizeof(float);
    const bool   use_tbuf   = ws_size >= need_tbuf;

    hipMemsetAsync(d_out, 0, (size_t)N_NODES * OUT_DIM * sizeof(float), stream);
    hipMemsetAsync(colflag, 0, (size_t)(N_NODES + 2) * sizeof(int), stream);

    packw_kernel<<<32, 256, 0, stream>>>(W, wp);

    gemm_kernel<<<(N_NODES + 63) / 64, 512, 0, stream>>>(x, wp, b, a, s_src, s_dst);

    edge_score_kernel<<<NBLK_RED, 256, 0, stream>>>(
        ei, s_src, s_dst, use_tbuf ? tbuf : nullptr, partial);

    finalize_kernel<<<1, 256, 0, stream>>>(partial, gate, coef, NBLK_RED);

    if (use_tbuf) {
        mark_flags_kernel<<<(N_EDGES + 255) / 256, 256, 0, stream>>>(
            ei, tbuf, coef, colflag);
        compact_nodes_kernel<<<(N_NODES + 255) / 256, 256, 0, stream>>>(
            colflag, ncount, nlist);
    } else {
        mark_kernel<<<(N_EDGES + 255) / 256, 256, 0, stream>>>(
            ei, s_src, s_dst, coef, elist, colflag, ecount, ncount, nlist);
    }

    whrows_kernel<<<(N_NODES + 63) / 64, 512, 0, stream>>>(
        x, wp, b, nlist, ncount, Wh);

    if (use_tbuf)
        acc_st_kernel<<<(N_EDGES + 255) / 256, 256, 0, stream>>>(
            ei, tbuf, Wh, coef, out);
    else
        acc_kernel<<<256, 256, 0, stream>>>(
            ei, s_src, s_dst, Wh, coef, elist, ecount, out);
}

// Round 8
// 232.262 us; speedup vs baseline: 1.7318x; 1.0168x over previous
//
#include <hip/hip_runtime.h>
#include <hip/hip_bf16.h>

// EGA layer (GAT-like, GLOBAL per-head softmax over edges) on MI355X.
// Pipeline:
//   packw -> MFMA split-GEMM (scores ONLY, no Wh store) -> edge score pass
//   (writes t-buffer + online (m,l) partials) -> finalize -> mark_flags
//   (coalesced threshold pass, PLAIN colflag stores, ZERO atomics) ->
//   compact_nodes (196 block-level atomics) -> whrows (MFMA bf16x3 Wh
//   recompute for marked cols only) -> acc_st (stream tbuf, inline re-test,
//   scatter passing edges).
// r7 evidence: gemm latency-bound on x fill (4 sequential load->convert
// rounds, ~0.6 TB/s effective; VGPR collapsed to 84). This round: two-phase
// fill (issue ALL loads -> sched_barrier(0) -> convert+write) in gemm/whrows.
// Worst case (flat scores) degrades to one extra full MFMA GEMM: bounded.

#define N_NODES 50000
#define N_EDGES 800000
#define IN_DIM  256
#define OUT_DIM 64
#define HEADS   8
#define NCOL    (HEADS * OUT_DIM)   // 512
#define NBLK_RED 2048               // partial-reduction blocks for edge softmax
#define LN_W_EPS (-20.72326584f)    // ln(1e-9) skip threshold

typedef __attribute__((ext_vector_type(8))) short short8;   // 8 x bf16 (4 VGPRs)
typedef __attribute__((ext_vector_type(4))) float f32x4;

// RNE bf16 hi + trunc bf16 lo split of 2 floats -> packed u32s (lane-order j, j+1)
__device__ __forceinline__ void bf16_split2(float x0, float x1,
                                            unsigned& hi, unsigned& lo)
{
    unsigned u0 = __float_as_uint(x0), u1 = __float_as_uint(x1);
    unsigned r0 = u0 + 0x7FFFu + ((u0 >> 16) & 1u);   // RNE to bf16
    unsigned r1 = u1 + 0x7FFFu + ((u1 >> 16) & 1u);
    float h0 = __uint_as_float(r0 & 0xFFFF0000u);
    float h1 = __uint_as_float(r1 & 0xFFFF0000u);
    hi = (r0 >> 16) | (r1 & 0xFFFF0000u);
    unsigned l0 = __float_as_uint(x0 - h0);           // residual, trunc to bf16
    unsigned l1 = __float_as_uint(x1 - h1);
    lo = (l0 >> 16) | (l1 & 0xFFFF0000u);
}

// ---------------------------------------------------------------------------
// Pack W (fp32 [8][256][64]) into B-fragment layout, bf16 hi/lo.
// B fragment for mfma_16x16x32: lane l -> col=l&15, k=(l>>4)*8+j  => a wave's
// fragment read is 1KB contiguous. Total 512 KB, stays L2-resident.
// ---------------------------------------------------------------------------
__global__ __launch_bounds__(256) void packw_kernel(
    const float* __restrict__ W, short* __restrict__ wp)
{
    const int ct = blockIdx.x;            // 0..31
    const int h  = ct >> 2;               // head (4 col-tiles per head)
    #pragma unroll
    for (int it = 0; it < 2; ++it) {
        const int i  = threadIdx.x + it * 256;   // 512 items: (k8, c)
        const int k8 = i >> 4;
        const int c  = i & 15;
        const int o  = (ct & 3) * 16 + c;
        const float* src = W + (size_t)h * IN_DIM * OUT_DIM
                             + (size_t)k8 * 8 * OUT_DIM + o;
        unsigned hi[4], lo[4];
        #pragma unroll
        for (int p = 0; p < 4; ++p) {
            float x0 = src[(2 * p) * OUT_DIM];
            float x1 = src[(2 * p + 1) * OUT_DIM];
            bf16_split2(x0, x1, hi[p], lo[p]);
        }
        uint4 vh = make_uint4(hi[0], hi[1], hi[2], hi[3]);
        uint4 vl = make_uint4(lo[0], lo[1], lo[2], lo[3]);
        *(uint4*)(wp + (((size_t)(ct * 2 + 0) * 32 + k8) * 128) + c * 8) = vh;
        *(uint4*)(wp + (((size_t)(ct * 2 + 1) * 32 + k8) * 128) + c * 8) = vl;
    }
}

// ---------------------------------------------------------------------------
// MFMA GEMM, SCORES ONLY. 512 threads = 8 waves; wave == head; one 64-row
// x-panel staged ONCE per block (serves all 8 heads), bf16 hi/lo, XOR-swizzle.
// TWO-PHASE fill: all 8 f32x4 loads issued first (128B/thread in flight ->
// HBM-saturating), sched_barrier(0) fence, then convert + LDS write.
// ---------------------------------------------------------------------------
__global__ __launch_bounds__(512, 2) void gemm_kernel(
    const float* __restrict__ x, const short* __restrict__ wp,
    const float* __restrict__ b, const float* __restrict__ a,
    float* __restrict__ s_src, float* __restrict__ s_dst)
{
    // [mi(4)][s(2)][k8(32)][r(16)][j(8)] halfs, 16B chunk index XOR-swizzled
    __shared__ __align__(16) short As[32768];        // 64 KB
    __shared__ __align__(16) float s_tmp[2][64][8];  // 4 KB score staging

    const int row0 = blockIdx.x * 64;
    const int tid  = threadIdx.x;
    const int lane = tid & 63;
    const int head = tid >> 6;            // wave == head 0..7
    const int r16  = lane & 15;
    const int kq   = lane >> 4;

    // ---- prefetch B[ks=0] before the fill: L2 latency hides under fill ----
    const short* pB = wp + (size_t)kq * 128 + (size_t)r16 * 8;
    #define LD_B(ni, s, ks) \
        (*(const short8*)(pB + ((((size_t)(head * 4 + (ni)) * 2 + (s)) * 32 + 4 * (ks)) * 128)))
    short8 Bh[2][4], Bl[2][4];
    #pragma unroll
    for (int ni = 0; ni < 4; ++ni) { Bh[0][ni] = LD_B(ni, 0, 0); Bl[0][ni] = LD_B(ni, 1, 0); }

    // ---- fill phase 1: issue ALL x loads (independent, 128B/thread) ----
    f32x4 vv[4][2];
    #pragma unroll
    for (int q = 0; q < 4; ++q) {
        const int item = q * 512 + tid;           // 2048 items: (row, kc)
        const int row  = item >> 5;               // 0..63
        const int kc   = item & 31;               // K-chunk of 8
        const int grow = row0 + row;
        vv[q][0] = (f32x4){0.f, 0.f, 0.f, 0.f};
        vv[q][1] = (f32x4){0.f, 0.f, 0.f, 0.f};
        if (grow < N_NODES) {
            vv[q][0] = *(const f32x4*)(x + (size_t)grow * IN_DIM + kc * 8);
            vv[q][1] = *(const f32x4*)(x + (size_t)grow * IN_DIM + kc * 8 + 4);
        }
    }
    __builtin_amdgcn_sched_barrier(0);   // keep loads clustered ahead of converts

    // ---- fill phase 2: convert + swizzled LDS write ----
    #pragma unroll
    for (int q = 0; q < 4; ++q) {
        const int item = q * 512 + tid;
        const int row  = item >> 5;
        const int kc   = item & 31;
        unsigned hi[4], lo[4];
        bf16_split2(vv[q][0].x, vv[q][0].y, hi[0], lo[0]);
        bf16_split2(vv[q][0].z, vv[q][0].w, hi[1], lo[1]);
        bf16_split2(vv[q][1].x, vv[q][1].y, hi[2], lo[2]);
        bf16_split2(vv[q][1].z, vv[q][1].w, hi[3], lo[3]);
        const int mi  = row >> 4, rr = row & 15;
        const int swz = rr ^ (kc & 15);
        uint4 vh = make_uint4(hi[0], hi[1], hi[2], hi[3]);
        uint4 vl = make_uint4(lo[0], lo[1], lo[2], lo[3]);
        *(uint4*)((char*)As + ((((mi * 2 + 0) * 32 + kc) * 16 + swz) * 16)) = vh;
        *(uint4*)((char*)As + ((((mi * 2 + 1) * 32 + kc) * 16 + swz) * 16)) = vl;
    }
    __syncthreads();

    // ---- K-loop (verified r1/r2 structure) ----
    f32x4 acc[4][4] = {};

    #define LD_A(mi, s, ks) \
        (*(const short8*)((const char*)As + \
            (((((mi) * 2 + (s)) * 32 + (4 * (ks) + kq)) * 16 + \
              (r16 ^ ((4 * ((ks) & 3) + kq)))) * 16)))

    short8 Ah[2][4], Al[2][4];
    #pragma unroll
    for (int mi = 0; mi < 4; ++mi) { Ah[0][mi] = LD_A(mi, 0, 0); Al[0][mi] = LD_A(mi, 1, 0); }

    #pragma unroll
    for (int ks = 0; ks < 8; ++ks) {
        const int cur = ks & 1, nxt = cur ^ 1;
        if (ks < 7) {
            #pragma unroll
            for (int ni = 0; ni < 4; ++ni) {
                Bh[nxt][ni] = LD_B(ni, 0, ks + 1);
                Bl[nxt][ni] = LD_B(ni, 1, ks + 1);
            }
            #pragma unroll
            for (int mi = 0; mi < 4; ++mi) {
                Ah[nxt][mi] = LD_A(mi, 0, ks + 1);
                Al[nxt][mi] = LD_A(mi, 1, ks + 1);
            }
        }
        #pragma unroll
        for (int mi = 0; mi < 4; ++mi)
            #pragma unroll
            for (int ni = 0; ni < 4; ++ni) {
                acc[mi][ni] = __builtin_amdgcn_mfma_f32_16x16x32_bf16(
                    Ah[cur][mi], Bh[cur][ni], acc[mi][ni], 0, 0, 0);
                acc[mi][ni] = __builtin_amdgcn_mfma_f32_16x16x32_bf16(
                    Ah[cur][mi], Bl[cur][ni], acc[mi][ni], 0, 0, 0);
                acc[mi][ni] = __builtin_amdgcn_mfma_f32_16x16x32_bf16(
                    Al[cur][mi], Bh[cur][ni], acc[mi][ni], 0, 0, 0);
            }
    }
    #undef LD_A
    #undef LD_B

    // ---- epilogue: fused score dot-products only (no Wh store) ----
    // C layout (verified): col = lane&15, row = (lane>>4)*4 + reg
    const int n0 = head * 64;
    float bias[4], avs[4], avd[4];
    #pragma unroll
    for (int ni = 0; ni < 4; ++ni) {
        bias[ni] = b[n0 + ni * 16 + r16];
        avs[ni]  = a[head * 128 + ni * 16 + r16];
        avd[ni]  = a[head * 128 + 64 + ni * 16 + r16];
    }
    #pragma unroll
    for (int mi = 0; mi < 4; ++mi) {
        #pragma unroll
        for (int reg = 0; reg < 4; ++reg) {
            float ps = 0.f, pd = 0.f;
            #pragma unroll
            for (int ni = 0; ni < 4; ++ni) {
                const float v = acc[mi][ni][reg] + bias[ni];
                ps += v * avs[ni];
                pd += v * avd[ni];
            }
            ps += __shfl_xor(ps, 1); pd += __shfl_xor(pd, 1);
            ps += __shfl_xor(ps, 2); pd += __shfl_xor(pd, 2);
            ps += __shfl_xor(ps, 4); pd += __shfl_xor(pd, 4);
            ps += __shfl_xor(ps, 8); pd += __shfl_xor(pd, 8);
            if (r16 == 0) {
                const int rloc = mi * 16 + kq * 4 + reg;
                s_tmp[0][rloc][head] = ps;
                s_tmp[1][rloc][head] = pd;
            }
        }
    }
    __syncthreads();
    if (tid < 256) {
        const int r   = tid & 63;
        const int sel = tid >> 6;            // 0..3: src-lo, src-hi, dst-lo, dst-hi
        const int gr  = row0 + r;
        if (gr < N_NODES) {
            float* dst = (sel < 2) ? s_src : s_dst;
            *(float4*)(dst + (size_t)gr * 8 + (sel & 1) * 4) =
                *(const float4*)&s_tmp[sel >> 1][r][(sel & 1) * 4];
        }
    }
}

// ---------------------------------------------------------------------------
// Edge score pass: lane-pair split (even lane: heads 0-3, odd: heads 4-7).
// Per edge-pair: ONE float4 gather per table per lane + half the per-lane
// online-softmax VALU. Writes t[8] coalesced to tbuf (if non-null) and
// per-block online (m,l) partials.
// ---------------------------------------------------------------------------
__global__ __launch_bounds__(256) void edge_score_kernel(
    const int* __restrict__ ei, const float* __restrict__ s_src,
    const float* __restrict__ s_dst, float* __restrict__ tbuf,
    float* __restrict__ partial)
{
    const int tid  = threadIdx.x;
    const int half = tid & 1;            // heads half*4 .. half*4+3

    float m[4], l[4];
    #pragma unroll
    for (int i = 0; i < 4; ++i) { m[i] = -1e30f; l[i] = 0.f; }

    for (int p = blockIdx.x * 128 + (tid >> 1); p < N_EDGES; p += gridDim.x * 128) {
        const int row = ei[p];
        const int col = ei[N_EDGES + p];
        const f32x4 s = *(const f32x4*)(s_src + row * 8 + half * 4);
        const f32x4 d = *(const f32x4*)(s_dst + col * 8 + half * 4);
        float t[4];
        #pragma unroll
        for (int i = 0; i < 4; ++i) {
            float v = s[i] + d[i];
            t[i] = v > 0.f ? v : 0.01f * v;       // leaky_relu 0.01
        }
        if (tbuf)
            *(float4*)(tbuf + (size_t)p * 8 + half * 4) =
                make_float4(t[0], t[1], t[2], t[3]);
        #pragma unroll
        for (int i = 0; i < 4; ++i) {
            const float mn = fmaxf(m[i], t[i]);
            l[i] = l[i] * __expf(m[i] - mn) + __expf(t[i] - mn);
            m[i] = mn;
        }
    }

    // block reduce; parity-preserving strides keep head mapping intact
    __shared__ float red[8][256];
    #pragma unroll
    for (int i = 0; i < 4; ++i) { red[i][tid] = m[i]; red[4 + i][tid] = l[i]; }
    __syncthreads();
    for (int s = 128; s >= 2; s >>= 1) {
        if (tid < s) {
            #pragma unroll
            for (int i = 0; i < 4; ++i) {
                const float mo = red[i][tid + s], lo = red[4 + i][tid + s];
                const float mm = red[i][tid],     ll = red[4 + i][tid];
                const float mn = fmaxf(mm, mo);
                red[4 + i][tid] = ll * __expf(mm - mn) + lo * __expf(mo - mn);
                red[i][tid]     = mn;
            }
        }
        __syncthreads();
    }
    if (tid < 2) {
        #pragma unroll
        for (int i = 0; i < 4; ++i) {
            partial[blockIdx.x * 16 + tid * 4 + i]     = red[i][tid];
            partial[blockIdx.x * 16 + 8 + tid * 4 + i] = red[4 + i][tid];
        }
    }
}

// ---------------------------------------------------------------------------
// Merge partials. coef[h]=M_h, coef[8+h]=g_h/L_h, coef[16+h]=skip cutoff.
// ---------------------------------------------------------------------------
__global__ __launch_bounds__(256) void finalize_kernel(
    const float* __restrict__ partial, const float* __restrict__ gate,
    float* __restrict__ coef, int nblk)
{
    const int t = threadIdx.x;
    const int h = t & 7;
    const int j = t >> 3;                 // 0..31
    float m = -1e30f, l = 0.f;
    for (int bk = j; bk < nblk; bk += 32) {
        const float mb = partial[bk * 16 + h];
        const float lb = partial[bk * 16 + 8 + h];
        const float mn = fmaxf(m, mb);
        l = l * __expf(m - mn) + lb * __expf(mb - mn);
        m = mn;
    }
    __shared__ float rm[256], rl[256];
    rm[t] = m; rl[t] = l;
    __syncthreads();
    for (int s = 128; s >= 8; s >>= 1) {
        if (t < s) {
            const float mo = rm[t + s], lo = rl[t + s];
            const float mn = fmaxf(rm[t], mo);
            rl[t] = rl[t] * __expf(rm[t] - mn) + lo * __expf(mo - mn);
            rm[t] = mn;
        }
        __syncthreads();
    }
    if (t < 8) {
        float gm = gate[0];
        for (int i = 1; i < 8; ++i) gm = fmaxf(gm, gate[i]);
        float gs = 0.f;
        for (int i = 0; i < 8; ++i) gs += __expf(gate[i] - gm);
        const float g = __expf(gate[t] - gm) / gs;
        const float C = g / rl[t];
        coef[t]      = rm[t];
        coef[8 + t]  = C;
        coef[16 + t] = rm[t] + LN_W_EPS - __logf(C);   // t >= cut  <=>  w >= eps
    }
}

// ---------------------------------------------------------------------------
// mark_flags: coalesced threshold pass over tbuf with ZERO atomics.
// Passing lanes plain-store colflag[col]=1 (benign race: all writers store 1).
// ---------------------------------------------------------------------------
__global__ __launch_bounds__(256) void mark_flags_kernel(
    const int* __restrict__ ei, const float* __restrict__ tbuf,
    const float* __restrict__ coef, int* __restrict__ colflag)
{
    __shared__ float cCut[8];
    if (threadIdx.x < 8) cCut[threadIdx.x] = coef[16 + threadIdx.x];
    __syncthreads();

    const int e = blockIdx.x * 256 + threadIdx.x;
    if (e >= N_EDGES) return;
    const float4 t0 = *(const float4*)(tbuf + (size_t)e * 8);
    const float4 t1 = *(const float4*)(tbuf + (size_t)e * 8 + 4);
    const bool pass =
        (t0.x >= cCut[0]) | (t0.y >= cCut[1]) |
        (t0.z >= cCut[2]) | (t0.w >= cCut[3]) |
        (t1.x >= cCut[4]) | (t1.y >= cCut[5]) |
        (t1.z >= cCut[6]) | (t1.w >= cCut[7]);
    if (pass)
        colflag[ei[N_EDGES + e]] = 1;     // plain store, no atomic
}

// ---------------------------------------------------------------------------
// compact_nodes: block-level ballot compaction of colflag into nlist.
// ONE atomicAdd per block (196 total) -- negligible contention.
// ---------------------------------------------------------------------------
__global__ __launch_bounds__(256) void compact_nodes_kernel(
    const int* __restrict__ colflag, int* __restrict__ ncount,
    int* __restrict__ nlist)
{
    const int n    = blockIdx.x * 256 + threadIdx.x;
    const int lane = threadIdx.x & 63;
    const int w    = threadIdx.x >> 6;
    const bool f   = (n < N_NODES) && (colflag[n] != 0);
    const unsigned long long mask = __ballot(f);

    __shared__ int wcnt[4];
    __shared__ int bbase;
    if (lane == 0) wcnt[w] = (int)__popcll(mask);
    __syncthreads();
    if (threadIdx.x == 0) {
        const int tot = wcnt[0] + wcnt[1] + wcnt[2] + wcnt[3];
        bbase = tot ? atomicAdd(ncount, tot) : 0;
    }
    __syncthreads();
    if (f) {
        int wbase = bbase;
        for (int i = 0; i < w; ++i) wbase += wcnt[i];
        const int rank = (int)__popcll(mask & ((1ULL << lane) - 1ULL));
        nlist[wbase + rank] = n;
    }
}

// ---------------------------------------------------------------------------
// Fallback mark (no tbuf space): r5-verified gather version.
// ---------------------------------------------------------------------------
__global__ __launch_bounds__(256) void mark_kernel(
    const int* __restrict__ ei, const float* __restrict__ s_src,
    const float* __restrict__ s_dst, const float* __restrict__ coef,
    int* __restrict__ elist, int* __restrict__ colflag,
    int* __restrict__ ecount, int* __restrict__ ncount, int* __restrict__ nlist)
{
    __shared__ float cCut[8];
    if (threadIdx.x < 8) cCut[threadIdx.x] = coef[16 + threadIdx.x];
    __syncthreads();

    const int e = blockIdx.x * 256 + threadIdx.x;
    bool pass = false;
    int col = 0;
    if (e < N_EDGES) {
        const int row = ei[e];
        col = ei[N_EDGES + e];
        const float4 s0 = *(const float4*)(s_src + row * 8);
        const float4 s1 = *(const float4*)(s_src + row * 8 + 4);
        const float4 d0 = *(const float4*)(s_dst + col * 8);
        const float4 d1 = *(const float4*)(s_dst + col * 8 + 4);
        float t[8] = { s0.x + d0.x, s0.y + d0.y, s0.z + d0.z, s0.w + d0.w,
                       s1.x + d1.x, s1.y + d1.y, s1.z + d1.z, s1.w + d1.w };
        #pragma unroll
        for (int h = 0; h < 8; ++h) {
            t[h] = t[h] > 0.f ? t[h] : 0.01f * t[h];
            pass |= (t[h] >= cCut[h]);
        }
    }

    const unsigned long long mask = __ballot(pass);
    if (mask) {
        const int lane   = threadIdx.x & 63;
        const int leader = (int)__builtin_ctzll(mask);
        int base = 0;
        if (lane == leader) base = atomicAdd(ecount, (int)__popcll(mask));
        base = __shfl(base, leader);
        if (pass) {
            const int rank = (int)__popcll(mask & ((1ULL << lane) - 1ULL));
            elist[base + rank] = e;
            if (atomicExch(&colflag[col], 1) == 0) {
                const int ni = atomicAdd(ncount, 1);
                nlist[ni] = col;
            }
        }
    }
}

// ---------------------------------------------------------------------------
// Wh recompute for marked cols only -- SAME verified MFMA bf16x3 block as the
// score GEMM, row indices indirected through the compacted nlist. Early exit
// past ncount. Wh stored PERMUTED (element (h,o) at h*64 + (o&15)*4 + (o>>4)).
// Two-phase fill like gemm.
// ---------------------------------------------------------------------------
__global__ __launch_bounds__(512, 2) void whrows_kernel(
    const float* __restrict__ x, const short* __restrict__ wp,
    const float* __restrict__ b, const int* __restrict__ nlist,
    const int* __restrict__ ncount, float* __restrict__ Wh)
{
    __shared__ __align__(16) short As[32768];   // 64 KB
    __shared__ int nl_sh[64];

    const int nc   = *ncount;
    const int row0 = blockIdx.x * 64;
    if (row0 >= nc) return;

    const int tid  = threadIdx.x;
    const int lane = tid & 63;
    const int head = tid >> 6;            // wave == head 0..7
    const int r16  = lane & 15;
    const int kq   = lane >> 4;

    if (tid < 64) {
        const int idx = row0 + tid;
        nl_sh[tid] = (idx < nc) ? nlist[idx] : -1;
    }

    const short* pB = wp + (size_t)kq * 128 + (size_t)r16 * 8;
    #define LD_B2(ni, s, ks) \
        (*(const short8*)(pB + ((((size_t)(head * 4 + (ni)) * 2 + (s)) * 32 + 4 * (ks)) * 128)))
    short8 Bh[2][4], Bl[2][4];
    #pragma unroll
    for (int ni = 0; ni < 4; ++ni) { Bh[0][ni] = LD_B2(ni, 0, 0); Bl[0][ni] = LD_B2(ni, 1, 0); }

    __syncthreads();   // nl_sh visible to fill

    // phase 1: issue all x loads
    f32x4 vv[4][2];
    #pragma unroll
    for (int q = 0; q < 4; ++q) {
        const int item = q * 512 + tid;
        const int row  = item >> 5;
        const int grow = nl_sh[row];
        const int kc   = item & 31;
        vv[q][0] = (f32x4){0.f, 0.f, 0.f, 0.f};
        vv[q][1] = (f32x4){0.f, 0.f, 0.f, 0.f};
        if (grow >= 0) {
            vv[q][0] = *(const f32x4*)(x + (size_t)grow * IN_DIM + kc * 8);
            vv[q][1] = *(const f32x4*)(x + (size_t)grow * IN_DIM + kc * 8 + 4);
        }
    }
    __builtin_amdgcn_sched_barrier(0);

    // phase 2: convert + swizzled LDS write
    #pragma unroll
    for (int q = 0; q < 4; ++q) {
        const int item = q * 512 + tid;
        const int row  = item >> 5;
        const int kc   = item & 31;
        unsigned hi[4], lo[4];
        bf16_split2(vv[q][0].x, vv[q][0].y, hi[0], lo[0]);
        bf16_split2(vv[q][0].z, vv[q][0].w, hi[1], lo[1]);
        bf16_split2(vv[q][1].x, vv[q][1].y, hi[2], lo[2]);
        bf16_split2(vv[q][1].z, vv[q][1].w, hi[3], lo[3]);
        const int mi  = row >> 4, rr = row & 15;
        const int swz = rr ^ (kc & 15);
        uint4 vh = make_uint4(hi[0], hi[1], hi[2], hi[3]);
        uint4 vl = make_uint4(lo[0], lo[1], lo[2], lo[3]);
        *(uint4*)((char*)As + ((((mi * 2 + 0) * 32 + kc) * 16 + swz) * 16)) = vh;
        *(uint4*)((char*)As + ((((mi * 2 + 1) * 32 + kc) * 16 + swz) * 16)) = vl;
    }
    __syncthreads();

    f32x4 acc[4][4] = {};

    #define LD_A2(mi, s, ks) \
        (*(const short8*)((const char*)As + \
            (((((mi) * 2 + (s)) * 32 + (4 * (ks) + kq)) * 16 + \
              (r16 ^ ((4 * ((ks) & 3) + kq)))) * 16)))

    short8 Ah[2][4], Al[2][4];
    #pragma unroll
    for (int mi = 0; mi < 4; ++mi) { Ah[0][mi] = LD_A2(mi, 0, 0); Al[0][mi] = LD_A2(mi, 1, 0); }

    #pragma unroll
    for (int ks = 0; ks < 8; ++ks) {
        const int cur = ks & 1, nxt = cur ^ 1;
        if (ks < 7) {
            #pragma unroll
            for (int ni = 0; ni < 4; ++ni) {
                Bh[nxt][ni] = LD_B2(ni, 0, ks + 1);
                Bl[nxt][ni] = LD_B2(ni, 1, ks + 1);
            }
            #pragma unroll
            for (int mi = 0; mi < 4; ++mi) {
                Ah[nxt][mi] = LD_A2(mi, 0, ks + 1);
                Al[nxt][mi] = LD_A2(mi, 1, ks + 1);
            }
        }
        #pragma unroll
        for (int mi = 0; mi < 4; ++mi)
            #pragma unroll
            for (int ni = 0; ni < 4; ++ni) {
                acc[mi][ni] = __builtin_amdgcn_mfma_f32_16x16x32_bf16(
                    Ah[cur][mi], Bh[cur][ni], acc[mi][ni], 0, 0, 0);
                acc[mi][ni] = __builtin_amdgcn_mfma_f32_16x16x32_bf16(
                    Ah[cur][mi], Bl[cur][ni], acc[mi][ni], 0, 0, 0);
                acc[mi][ni] = __builtin_amdgcn_mfma_f32_16x16x32_bf16(
                    Al[cur][mi], Bh[cur][ni], acc[mi][ni], 0, 0, 0);
            }
    }
    #undef LD_A2
    #undef LD_B2

    // epilogue: permuted-layout float4 Wh stores for valid rows
    const int n0 = head * 64;
    float bias[4];
    #pragma unroll
    for (int ni = 0; ni < 4; ++ni) bias[ni] = b[n0 + ni * 16 + r16];

    #pragma unroll
    for (int mi = 0; mi < 4; ++mi) {
        #pragma unroll
        for (int reg = 0; reg < 4; ++reg) {
            const int rloc = mi * 16 + kq * 4 + reg;
            const int n    = nl_sh[rloc];
            if (n >= 0) {
                *(float4*)(Wh + (size_t)n * NCOL + n0 + r16 * 4) =
                    make_float4(acc[mi][0][reg] + bias[0],
                                acc[mi][1][reg] + bias[1],
                                acc[mi][2][reg] + bias[2],
                                acc[mi][3][reg] + bias[3]);
            }
        }
    }
}

// ---------------------------------------------------------------------------
// acc_st: stream tbuf coalesced, re-test cut inline, load ei only for passing
// lanes, wave-cooperative gather of permuted Wh[col], atomicAdd out.
// ---------------------------------------------------------------------------
__global__ __launch_bounds__(256) void acc_st_kernel(
    const int* __restrict__ ei, const float* __restrict__ tbuf,
    const float* __restrict__ Wh, const float* __restrict__ coef,
    float* __restrict__ out)
{
    __shared__ float cM[8], cC[8], cCut[8];
    if (threadIdx.x < 8)       cM[threadIdx.x]        = coef[threadIdx.x];
    else if (threadIdx.x < 16) cC[threadIdx.x - 8]    = coef[threadIdx.x];
    else if (threadIdx.x < 24) cCut[threadIdx.x - 16] = coef[threadIdx.x];
    __syncthreads();

    const int lane = threadIdx.x & 63;
    const int e    = blockIdx.x * 256 + threadIdx.x;

    bool pass = false;
    float t[8];
    if (e < N_EDGES) {
        const float4 t0 = *(const float4*)(tbuf + (size_t)e * 8);
        const float4 t1 = *(const float4*)(tbuf + (size_t)e * 8 + 4);
        t[0] = t0.x; t[1] = t0.y; t[2] = t0.z; t[3] = t0.w;
        t[4] = t1.x; t[5] = t1.y; t[6] = t1.z; t[7] = t1.w;
        #pragma unroll
        for (int h = 0; h < 8; ++h) pass |= (t[h] >= cCut[h]);
    }

    int row = 0, col = 0;
    float wgt[8];
    if (pass) {
        row = ei[e];
        col = ei[N_EDGES + e];
        #pragma unroll
        for (int h = 0; h < 8; ++h)
            wgt[h] = __expf(t[h] - cM[h]) * cC[h];
    }

    unsigned long long mask = __ballot(pass);
    while (mask) {
        const int src = (int)__builtin_ctzll(mask);
        mask &= mask - 1;
        const int rb = __shfl(row, src);
        const int cb = __shfl(col, src);
        // permuted Wh row: element (h, o) at h*64 + (o&15)*4 + (o>>4); o == lane
        const float* wc = Wh + (size_t)cb * NCOL + (lane & 15) * 4 + (lane >> 4);
        float acc = 0.f;
        #pragma unroll
        for (int h = 0; h < 8; ++h)
            acc += __shfl(wgt[h], src) * wc[h * 64];
        atomicAdd(out + (size_t)rb * OUT_DIM + lane, acc);
    }
}

// ---------------------------------------------------------------------------
// Fallback acc (no tbuf): r5-verified gather version over elist.
// ---------------------------------------------------------------------------
__global__ __launch_bounds__(256) void acc_kernel(
    const int* __restrict__ ei, const float* __restrict__ s_src,
    const float* __restrict__ s_dst, const float* __restrict__ Wh,
    const float* __restrict__ coef, const int* __restrict__ elist,
    const int* __restrict__ ecount, float* __restrict__ out)
{
    __shared__ float cM[8], cC[8];
    if (threadIdx.x < 8)       cM[threadIdx.x]     = coef[threadIdx.x];
    else if (threadIdx.x < 16) cC[threadIdx.x - 8] = coef[threadIdx.x];
    __syncthreads();

    const int n    = *ecount;
    const int lane = threadIdx.x & 63;

    for (int i = blockIdx.x * 256 + threadIdx.x; ; i += gridDim.x * 256) {
        const bool has = i < n;
        if (!__any(has)) break;

        int row = 0, col = 0;
        float wgt[8];
        if (has) {
            const int e = elist[i];
            row = ei[e];
            col = ei[N_EDGES + e];
            const float4 s0 = *(const float4*)(s_src + row * 8);
            const float4 s1 = *(const float4*)(s_src + row * 8 + 4);
            const float4 d0 = *(const float4*)(s_dst + col * 8);
            const float4 d1 = *(const float4*)(s_dst + col * 8 + 4);
            float t[8] = { s0.x + d0.x, s0.y + d0.y, s0.z + d0.z, s0.w + d0.w,
                           s1.x + d1.x, s1.y + d1.y, s1.z + d1.z, s1.w + d1.w };
            #pragma unroll
            for (int h = 0; h < 8; ++h) {
                t[h] = t[h] > 0.f ? t[h] : 0.01f * t[h];
                wgt[h] = __expf(t[h] - cM[h]) * cC[h];
            }
        }

        unsigned long long mask = __ballot(has);
        while (mask) {
            const int src = (int)__builtin_ctzll(mask);
            mask &= mask - 1;
            const int rb = __shfl(row, src);
            const int cb = __shfl(col, src);
            const float* wc = Wh + (size_t)cb * NCOL + (lane & 15) * 4 + (lane >> 4);
            float acc = 0.f;
            #pragma unroll
            for (int h = 0; h < 8; ++h)
                acc += __shfl(wgt[h], src) * wc[h * 64];
            atomicAdd(out + (size_t)rb * OUT_DIM + lane, acc);
        }
    }
}

// ---------------------------------------------------------------------------
extern "C" void kernel_launch(void* const* d_in, const int* in_sizes, int n_in,
                              void* d_out, int out_size, void* d_ws, size_t ws_size,
                              hipStream_t stream)
{
    const float* x    = (const float*)d_in[0];
    const int*   ei   = (const int*)  d_in[1];
    const float* W    = (const float*)d_in[2];
    const float* b    = (const float*)d_in[3];
    const float* a    = (const float*)d_in[4];
    const float* gate = (const float*)d_in[5];
    float* out = (float*)d_out;

    // workspace (floats): Wh | s_src | s_dst | partial | coef | wp | elist |
    //                     colflag | ecount | ncount | nlist | tbuf  (~135 MB)
    float* ws      = (float*)d_ws;
    float* Wh      = ws;
    float* s_src   = Wh    + (size_t)N_NODES * NCOL;
    float* s_dst   = s_src + (size_t)N_NODES * HEADS;
    float* partial = s_dst + (size_t)N_NODES * HEADS;
    float* coef    = partial + (size_t)NBLK_RED * 16;
    short* wp      = (short*)(coef + 32);              // 512 KB, 16B-aligned
    int*   elist   = (int*)(wp + 262144);              // 800K ints (fallback only)
    int*   colflag = elist + N_EDGES;                  // 50K ints
    int*   ecount  = colflag + N_NODES;                // 1 int
    int*   ncount  = ecount + 1;                       // 1 int
    int*   nlist   = ncount + 1;                       // 50K ints
    float* tbuf    = (float*)(nlist + N_NODES);        // 25.6 MB (optional)

    const size_t base_bytes = (size_t)((char*)tbuf - (char*)ws);
    const size_t need_tbuf  = base_bytes + (size_t)N_EDGES * 8 * sizeof(float);
    const bool   use_tbuf   = ws_size >= need_tbuf;

    hipMemsetAsync(d_out, 0, (size_t)N_NODES * OUT_DIM * sizeof(float), stream);
    hipMemsetAsync(colflag, 0, (size_t)(N_NODES + 2) * sizeof(int), stream);

    packw_kernel<<<32, 256, 0, stream>>>(W, wp);

    gemm_kernel<<<(N_NODES + 63) / 64, 512, 0, stream>>>(x, wp, b, a, s_src, s_dst);

    edge_score_kernel<<<NBLK_RED, 256, 0, stream>>>(
        ei, s_src, s_dst, use_tbuf ? tbuf : nullptr, partial);

    finalize_kernel<<<1, 256, 0, stream>>>(partial, gate, coef, NBLK_RED);

    if (use_tbuf) {
        mark_flags_kernel<<<(N_EDGES + 255) / 256, 256, 0, stream>>>(
            ei, tbuf, coef, colflag);
        compact_nodes_kernel<<<(N_NODES + 255) / 256, 256, 0, stream>>>(
            colflag, ncount, nlist);
    } else {
        mark_kernel<<<(N_EDGES + 255) / 256, 256, 0, stream>>>(
            ei, s_src, s_dst, coef, elist, colflag, ecount, ncount, nlist);
    }

    whrows_kernel<<<(N_NODES + 63) / 64, 512, 0, stream>>>(
        x, wp, b, nlist, ncount, Wh);

    if (use_tbuf)
        acc_st_kernel<<<(N_EDGES + 255) / 256, 256, 0, stream>>>(
            ei, tbuf, Wh, coef, out);
    else
        acc_kernel<<<256, 256, 0, stream>>>(
            ei, s_src, s_dst, Wh, coef, elist, ecount, out);
}

// Round 9
// 195.969 us; speedup vs baseline: 2.0525x; 1.1852x over previous
//
#include <hip/hip_runtime.h>
#include <hip/hip_bf16.h>

// EGA layer (GAT-like, GLOBAL per-head softmax over edges) on MI355X.
// Pipeline:
//   prep (u = W@a, c = b@a) -> packw -> score (x@u skinny matvec, fp32,
//   memory-bound: the 13.1 GFLOP score-GEMM is algebraically collapsible to
//   410 MFLOP since scores only need Wh THROUGH the a-dot) -> edge score pass
//   (unroll-4 gathers for MLP; writes t-buffer + online (m,l) partials) ->
//   finalize -> mark_flags (zero-atomic threshold pass) -> compact_nodes ->
//   whrows (MFMA bf16x3 Wh recompute for marked cols only) -> acc_st.
// Evidence: r5/r6 per-edge same-address atomics ~130us (removed r7); r7/r8
// gemm latency/LDS-bound at 70us -> replaced by algebraic collapse; edge
// passes are gather-latency-bound -> unroll-4 for 4x MLP.
// Worst case (flat scores) degrades to one full MFMA GEMM in whrows: bounded.

#define N_NODES 50000
#define N_EDGES 800000
#define IN_DIM  256
#define OUT_DIM 64
#define HEADS   8
#define NCOL    (HEADS * OUT_DIM)   // 512
#define ES_BLOCKS 1568              // edge_score blocks: 512 edges/block, unroll 4
#define LN_W_EPS (-20.72326584f)    // ln(1e-9) skip threshold

typedef __attribute__((ext_vector_type(8))) short short8;   // 8 x bf16 (4 VGPRs)
typedef __attribute__((ext_vector_type(4))) float f32x4;

// RNE bf16 hi + trunc bf16 lo split of 2 floats -> packed u32s (lane-order j, j+1)
__device__ __forceinline__ void bf16_split2(float x0, float x1,
                                            unsigned& hi, unsigned& lo)
{
    unsigned u0 = __float_as_uint(x0), u1 = __float_as_uint(x1);
    unsigned r0 = u0 + 0x7FFFu + ((u0 >> 16) & 1u);   // RNE to bf16
    unsigned r1 = u1 + 0x7FFFu + ((u1 >> 16) & 1u);
    float h0 = __uint_as_float(r0 & 0xFFFF0000u);
    float h1 = __uint_as_float(r1 & 0xFFFF0000u);
    hi = (r0 >> 16) | (r1 & 0xFFFF0000u);
    unsigned l0 = __float_as_uint(x0 - h0);           // residual, trunc to bf16
    unsigned l1 = __float_as_uint(x1 - h1);
    lo = (l0 >> 16) | (l1 & 0xFFFF0000u);
}

// ---------------------------------------------------------------------------
// prep: u[j][d] = sum_o W[h][d][o] * a[h][sd*64+o], j = sd*8+h (16 rows);
// c[j] = b[h]·a[h][sd*64..]. Output ug[0..4095] = u, ug[4096..4111] = c.
// ---------------------------------------------------------------------------
__global__ __launch_bounds__(256) void prep_kernel(
    const float* __restrict__ W, const float* __restrict__ b,
    const float* __restrict__ a, float* __restrict__ ug)
{
    const int j = blockIdx.x;            // 0..15
    const int h = j & 7, sd = j >> 3;
    __shared__ float a_sh[64];
    if (threadIdx.x < 64) a_sh[threadIdx.x] = a[h * 128 + sd * 64 + threadIdx.x];
    __syncthreads();

    const int d = threadIdx.x;           // 0..255
    const float* wrow = W + ((size_t)h * IN_DIM + d) * OUT_DIM;
    float s = 0.f;
    #pragma unroll 8
    for (int o = 0; o < 64; ++o) s += wrow[o] * a_sh[o];
    ug[j * 256 + d] = s;
    if (d == 0) {
        float c = 0.f;
        for (int o = 0; o < 64; ++o) c += b[h * OUT_DIM + o] * a_sh[o];
        ug[4096 + j] = c;
    }
}

// ---------------------------------------------------------------------------
// Pack W (fp32 [8][256][64]) into B-fragment layout, bf16 hi/lo (for whrows).
// ---------------------------------------------------------------------------
__global__ __launch_bounds__(256) void packw_kernel(
    const float* __restrict__ W, short* __restrict__ wp)
{
    const int ct = blockIdx.x;            // 0..31
    const int h  = ct >> 2;               // head (4 col-tiles per head)
    #pragma unroll
    for (int it = 0; it < 2; ++it) {
        const int i  = threadIdx.x + it * 256;   // 512 items: (k8, c)
        const int k8 = i >> 4;
        const int c  = i & 15;
        const int o  = (ct & 3) * 16 + c;
        const float* src = W + (size_t)h * IN_DIM * OUT_DIM
                             + (size_t)k8 * 8 * OUT_DIM + o;
        unsigned hi[4], lo[4];
        #pragma unroll
        for (int p = 0; p < 4; ++p) {
            float x0 = src[(2 * p) * OUT_DIM];
            float x1 = src[(2 * p + 1) * OUT_DIM];
            bf16_split2(x0, x1, hi[p], lo[p]);
        }
        uint4 vh = make_uint4(hi[0], hi[1], hi[2], hi[3]);
        uint4 vl = make_uint4(lo[0], lo[1], lo[2], lo[3]);
        *(uint4*)(wp + (((size_t)(ct * 2 + 0) * 32 + k8) * 128) + c * 8) = vh;
        *(uint4*)(wp + (((size_t)(ct * 2 + 1) * 32 + k8) * 128) + c * 8) = vl;
    }
}

// ---------------------------------------------------------------------------
// reduce-scatter butterfly: input p[16] per lane; output = full 64-lane sum
// of value jj on each lane, jj = bitrev4(lane&15). 17 shfls (vs 96 for the
// naive per-j butterfly). All index selects are static (rule: no runtime
// VGPR-array indexing).
// ---------------------------------------------------------------------------
__device__ __forceinline__ float reduce16x64(const float (&p)[16], int lane)
{
    float v8[8];
    #pragma unroll
    for (int j = 0; j < 8; ++j) {
        const float keep = (lane & 1) ? p[j + 8] : p[j];
        const float send = (lane & 1) ? p[j] : p[j + 8];
        v8[j] = keep + __shfl_xor(send, 1);
    }
    float v4[4];
    #pragma unroll
    for (int j = 0; j < 4; ++j) {
        const float keep = (lane & 2) ? v8[j + 4] : v8[j];
        const float send = (lane & 2) ? v8[j] : v8[j + 4];
        v4[j] = keep + __shfl_xor(send, 2);
    }
    float v2[2];
    #pragma unroll
    for (int j = 0; j < 2; ++j) {
        const float keep = (lane & 4) ? v4[j + 2] : v4[j];
        const float send = (lane & 4) ? v4[j] : v4[j + 2];
        v2[j] = keep + __shfl_xor(send, 4);
    }
    float v1;
    {
        const float keep = (lane & 8) ? v2[1] : v2[0];
        const float send = (lane & 8) ? v2[0] : v2[1];
        v1 = keep + __shfl_xor(send, 8);
    }
    v1 += __shfl_xor(v1, 16);
    v1 += __shfl_xor(v1, 32);
    return v1;
}

// ---------------------------------------------------------------------------
// score: s[n][j] = x[n,:]·u[j,:] + c[j] (j<8: src head j; j>=8: dst head j-8).
// Wave handles 16 nodes, 4 per iteration (64B/lane in flight -> HBM MLP).
// u held in 64 VGPRs per thread (f32x4 per j at this lane's d-quad) -- no LDS
// on the critical path. fp32 throughout (MORE accurate than bf16x3 scores).
// ---------------------------------------------------------------------------
__global__ __launch_bounds__(256, 2) void score_kernel(
    const float* __restrict__ x, const float* __restrict__ ug,
    float* __restrict__ s_src, float* __restrict__ s_dst)
{
    const int tid  = threadIdx.x;
    const int lane = tid & 63;
    const int w    = tid >> 6;
    const int jj   = ((lane & 1) << 3) | (((lane >> 1) & 1) << 2) |
                     (((lane >> 2) & 1) << 1) | ((lane >> 3) & 1);

    f32x4 uj[16];
    #pragma unroll
    for (int j = 0; j < 16; ++j)
        uj[j] = *(const f32x4*)(ug + j * 256 + lane * 4);
    const float cj = (lane < 16) ? ug[4096 + jj] : 0.f;

    const int base = (blockIdx.x * 4 + w) * 16;

    #pragma unroll
    for (int i0 = 0; i0 < 16; i0 += 4) {
        int   n[4];
        f32x4 xv[4];
        #pragma unroll
        for (int k = 0; k < 4; ++k) {
            n[k] = base + i0 + k;
            xv[k] = (f32x4){0.f, 0.f, 0.f, 0.f};
            if (n[k] < N_NODES)
                xv[k] = *(const f32x4*)(x + (size_t)n[k] * IN_DIM + lane * 4);
        }
        __builtin_amdgcn_sched_barrier(0);

        #pragma unroll
        for (int k = 0; k < 4; ++k) {
            float p[16];
            #pragma unroll
            for (int j = 0; j < 16; ++j)
                p[j] = xv[k].x * uj[j].x + xv[k].y * uj[j].y +
                       xv[k].z * uj[j].z + xv[k].w * uj[j].w;
            const float r = reduce16x64(p, lane);
            if (lane < 16 && n[k] < N_NODES) {
                const float val = r + cj;
                if (jj < 8) s_src[(size_t)n[k] * 8 + jj]       = val;
                else        s_dst[(size_t)n[k] * 8 + (jj - 8)] = val;
            }
        }
    }
}

// ---------------------------------------------------------------------------
// Edge score pass, UNROLL-4 for gather MLP: issue all 8 ei loads, then all 8
// table gathers (sched_barrier fences), then the VALU. Lane-pair split (even
// lane: heads 0-3, odd: heads 4-7). Writes t[8] coalesced to tbuf (if
// non-null) and per-block online (m,l) partials.
// ---------------------------------------------------------------------------
__global__ __launch_bounds__(256) void edge_score_kernel(
    const int* __restrict__ ei, const float* __restrict__ s_src,
    const float* __restrict__ s_dst, float* __restrict__ tbuf,
    float* __restrict__ partial)
{
    const int tid  = threadIdx.x;
    const int half = tid & 1;            // heads half*4 .. half*4+3
    const int e0   = blockIdx.x * 512 + (tid >> 1);

    int  pe[4], rows[4], cols[4];
    bool valid[4];
    #pragma unroll
    for (int i = 0; i < 4; ++i) {
        pe[i]    = e0 + i * 128;
        valid[i] = pe[i] < N_EDGES;
        rows[i]  = valid[i] ? ei[pe[i]] : 0;
        cols[i]  = valid[i] ? ei[N_EDGES + pe[i]] : 0;
    }
    __builtin_amdgcn_sched_barrier(0);

    f32x4 sv[4], dv[4];
    #pragma unroll
    for (int i = 0; i < 4; ++i) {
        sv[i] = *(const f32x4*)(s_src + rows[i] * 8 + half * 4);
        dv[i] = *(const f32x4*)(s_dst + cols[i] * 8 + half * 4);
    }
    __builtin_amdgcn_sched_barrier(0);

    float m[4], l[4];
    #pragma unroll
    for (int i = 0; i < 4; ++i) { m[i] = -1e30f; l[i] = 0.f; }

    #pragma unroll
    for (int i = 0; i < 4; ++i) {
        if (!valid[i]) continue;
        float t[4];
        #pragma unroll
        for (int q = 0; q < 4; ++q) {
            const float v = sv[i][q] + dv[i][q];
            t[q] = v > 0.f ? v : 0.01f * v;        // leaky_relu 0.01
        }
        if (tbuf)
            *(float4*)(tbuf + (size_t)pe[i] * 8 + half * 4) =
                make_float4(t[0], t[1], t[2], t[3]);
        #pragma unroll
        for (int q = 0; q < 4; ++q) {
            const float mn = fmaxf(m[q], t[q]);
            l[q] = l[q] * __expf(m[q] - mn) + __expf(t[q] - mn);
            m[q] = mn;
        }
    }

    // block reduce; parity-preserving strides keep head mapping intact
    __shared__ float red[8][256];
    #pragma unroll
    for (int q = 0; q < 4; ++q) { red[q][tid] = m[q]; red[4 + q][tid] = l[q]; }
    __syncthreads();
    for (int s = 128; s >= 2; s >>= 1) {
        if (tid < s) {
            #pragma unroll
            for (int q = 0; q < 4; ++q) {
                const float mo = red[q][tid + s], lo = red[4 + q][tid + s];
                const float mm = red[q][tid],     ll = red[4 + q][tid];
                const float mn = fmaxf(mm, mo);
                red[4 + q][tid] = ll * __expf(mm - mn) + lo * __expf(mo - mn);
                red[q][tid]     = mn;
            }
        }
        __syncthreads();
    }
    if (tid < 2) {
        #pragma unroll
        for (int q = 0; q < 4; ++q) {
            partial[blockIdx.x * 16 + tid * 4 + q]     = red[q][tid];
            partial[blockIdx.x * 16 + 8 + tid * 4 + q] = red[4 + q][tid];
        }
    }
}

// ---------------------------------------------------------------------------
// Merge partials. coef[h]=M_h, coef[8+h]=g_h/L_h, coef[16+h]=skip cutoff.
// ---------------------------------------------------------------------------
__global__ __launch_bounds__(256) void finalize_kernel(
    const float* __restrict__ partial, const float* __restrict__ gate,
    float* __restrict__ coef, int nblk)
{
    const int t = threadIdx.x;
    const int h = t & 7;
    const int j = t >> 3;                 // 0..31
    float m = -1e30f, l = 0.f;
    for (int bk = j; bk < nblk; bk += 32) {
        const float mb = partial[bk * 16 + h];
        const float lb = partial[bk * 16 + 8 + h];
        const float mn = fmaxf(m, mb);
        l = l * __expf(m - mn) + lb * __expf(mb - mn);
        m = mn;
    }
    __shared__ float rm[256], rl[256];
    rm[t] = m; rl[t] = l;
    __syncthreads();
    for (int s = 128; s >= 8; s >>= 1) {
        if (t < s) {
            const float mo = rm[t + s], lo = rl[t + s];
            const float mn = fmaxf(rm[t], mo);
            rl[t] = rl[t] * __expf(rm[t] - mn) + lo * __expf(mo - mn);
            rm[t] = mn;
        }
        __syncthreads();
    }
    if (t < 8) {
        float gm = gate[0];
        for (int i = 1; i < 8; ++i) gm = fmaxf(gm, gate[i]);
        float gs = 0.f;
        for (int i = 0; i < 8; ++i) gs += __expf(gate[i] - gm);
        const float g = __expf(gate[t] - gm) / gs;
        const float C = g / rl[t];
        coef[t]      = rm[t];
        coef[8 + t]  = C;
        coef[16 + t] = rm[t] + LN_W_EPS - __logf(C);   // t >= cut  <=>  w >= eps
    }
}

// ---------------------------------------------------------------------------
// mark_flags: coalesced threshold pass over tbuf with ZERO atomics.
// Passing lanes plain-store colflag[col]=1 (benign race: all writers store 1).
// ---------------------------------------------------------------------------
__global__ __launch_bounds__(256) void mark_flags_kernel(
    const int* __restrict__ ei, const float* __restrict__ tbuf,
    const float* __restrict__ coef, int* __restrict__ colflag)
{
    __shared__ float cCut[8];
    if (threadIdx.x < 8) cCut[threadIdx.x] = coef[16 + threadIdx.x];
    __syncthreads();

    const int e = blockIdx.x * 256 + threadIdx.x;
    if (e >= N_EDGES) return;
    const float4 t0 = *(const float4*)(tbuf + (size_t)e * 8);
    const float4 t1 = *(const float4*)(tbuf + (size_t)e * 8 + 4);
    const bool pass =
        (t0.x >= cCut[0]) | (t0.y >= cCut[1]) |
        (t0.z >= cCut[2]) | (t0.w >= cCut[3]) |
        (t1.x >= cCut[4]) | (t1.y >= cCut[5]) |
        (t1.z >= cCut[6]) | (t1.w >= cCut[7]);
    if (pass)
        colflag[ei[N_EDGES + e]] = 1;     // plain store, no atomic
}

// ---------------------------------------------------------------------------
// compact_nodes: block-level ballot compaction of colflag into nlist.
// ONE atomicAdd per block (196 total) -- negligible contention.
// ---------------------------------------------------------------------------
__global__ __launch_bounds__(256) void compact_nodes_kernel(
    const int* __restrict__ colflag, int* __restrict__ ncount,
    int* __restrict__ nlist)
{
    const int n    = blockIdx.x * 256 + threadIdx.x;
    const int lane = threadIdx.x & 63;
    const int w    = threadIdx.x >> 6;
    const bool f   = (n < N_NODES) && (colflag[n] != 0);
    const unsigned long long mask = __ballot(f);

    __shared__ int wcnt[4];
    __shared__ int bbase;
    if (lane == 0) wcnt[w] = (int)__popcll(mask);
    __syncthreads();
    if (threadIdx.x == 0) {
        const int tot = wcnt[0] + wcnt[1] + wcnt[2] + wcnt[3];
        bbase = tot ? atomicAdd(ncount, tot) : 0;
    }
    __syncthreads();
    if (f) {
        int wbase = bbase;
        for (int i = 0; i < w; ++i) wbase += wcnt[i];
        const int rank = (int)__popcll(mask & ((1ULL << lane) - 1ULL));
        nlist[wbase + rank] = n;
    }
}

// ---------------------------------------------------------------------------
// Fallback mark (no tbuf space): r5-verified gather version.
// ---------------------------------------------------------------------------
__global__ __launch_bounds__(256) void mark_kernel(
    const int* __restrict__ ei, const float* __restrict__ s_src,
    const float* __restrict__ s_dst, const float* __restrict__ coef,
    int* __restrict__ elist, int* __restrict__ colflag,
    int* __restrict__ ecount, int* __restrict__ ncount, int* __restrict__ nlist)
{
    __shared__ float cCut[8];
    if (threadIdx.x < 8) cCut[threadIdx.x] = coef[16 + threadIdx.x];
    __syncthreads();

    const int e = blockIdx.x * 256 + threadIdx.x;
    bool pass = false;
    int col = 0;
    if (e < N_EDGES) {
        const int row = ei[e];
        col = ei[N_EDGES + e];
        const float4 s0 = *(const float4*)(s_src + row * 8);
        const float4 s1 = *(const float4*)(s_src + row * 8 + 4);
        const float4 d0 = *(const float4*)(s_dst + col * 8);
        const float4 d1 = *(const float4*)(s_dst + col * 8 + 4);
        float t[8] = { s0.x + d0.x, s0.y + d0.y, s0.z + d0.z, s0.w + d0.w,
                       s1.x + d1.x, s1.y + d1.y, s1.z + d1.z, s1.w + d1.w };
        #pragma unroll
        for (int h = 0; h < 8; ++h) {
            t[h] = t[h] > 0.f ? t[h] : 0.01f * t[h];
            pass |= (t[h] >= cCut[h]);
        }
    }

    const unsigned long long mask = __ballot(pass);
    if (mask) {
        const int lane   = threadIdx.x & 63;
        const int leader = (int)__builtin_ctzll(mask);
        int base = 0;
        if (lane == leader) base = atomicAdd(ecount, (int)__popcll(mask));
        base = __shfl(base, leader);
        if (pass) {
            const int rank = (int)__popcll(mask & ((1ULL << lane) - 1ULL));
            elist[base + rank] = e;
            if (atomicExch(&colflag[col], 1) == 0) {
                const int ni = atomicAdd(ncount, 1);
                nlist[ni] = col;
            }
        }
    }
}

// ---------------------------------------------------------------------------
// Wh recompute for marked cols only -- verified MFMA bf16x3 block, row indices
// indirected through the compacted nlist. Early exit past ncount. Wh stored
// PERMUTED (element (h,o) at h*64 + (o&15)*4 + (o>>4)). Two-phase fill.
// Worst case (all nodes marked) = one full MFMA GEMM: bounded.
// ---------------------------------------------------------------------------
__global__ __launch_bounds__(512, 2) void whrows_kernel(
    const float* __restrict__ x, const short* __restrict__ wp,
    const float* __restrict__ b, const int* __restrict__ nlist,
    const int* __restrict__ ncount, float* __restrict__ Wh)
{
    __shared__ __align__(16) short As[32768];   // 64 KB
    __shared__ int nl_sh[64];

    const int nc   = *ncount;
    const int row0 = blockIdx.x * 64;
    if (row0 >= nc) return;

    const int tid  = threadIdx.x;
    const int lane = tid & 63;
    const int head = tid >> 6;            // wave == head 0..7
    const int r16  = lane & 15;
    const int kq   = lane >> 4;

    if (tid < 64) {
        const int idx = row0 + tid;
        nl_sh[tid] = (idx < nc) ? nlist[idx] : -1;
    }

    const short* pB = wp + (size_t)kq * 128 + (size_t)r16 * 8;
    #define LD_B2(ni, s, ks) \
        (*(const short8*)(pB + ((((size_t)(head * 4 + (ni)) * 2 + (s)) * 32 + 4 * (ks)) * 128)))
    short8 Bh[2][4], Bl[2][4];
    #pragma unroll
    for (int ni = 0; ni < 4; ++ni) { Bh[0][ni] = LD_B2(ni, 0, 0); Bl[0][ni] = LD_B2(ni, 1, 0); }

    __syncthreads();   // nl_sh visible to fill

    // phase 1: issue all x loads
    f32x4 vv[4][2];
    #pragma unroll
    for (int q = 0; q < 4; ++q) {
        const int item = q * 512 + tid;
        const int row  = item >> 5;
        const int grow = nl_sh[row];
        const int kc   = item & 31;
        vv[q][0] = (f32x4){0.f, 0.f, 0.f, 0.f};
        vv[q][1] = (f32x4){0.f, 0.f, 0.f, 0.f};
        if (grow >= 0) {
            vv[q][0] = *(const f32x4*)(x + (size_t)grow * IN_DIM + kc * 8);
            vv[q][1] = *(const f32x4*)(x + (size_t)grow * IN_DIM + kc * 8 + 4);
        }
    }
    __builtin_amdgcn_sched_barrier(0);

    // phase 2: convert + swizzled LDS write
    #pragma unroll
    for (int q = 0; q < 4; ++q) {
        const int item = q * 512 + tid;
        const int row  = item >> 5;
        const int kc   = item & 31;
        unsigned hi[4], lo[4];
        bf16_split2(vv[q][0].x, vv[q][0].y, hi[0], lo[0]);
        bf16_split2(vv[q][0].z, vv[q][0].w, hi[1], lo[1]);
        bf16_split2(vv[q][1].x, vv[q][1].y, hi[2], lo[2]);
        bf16_split2(vv[q][1].z, vv[q][1].w, hi[3], lo[3]);
        const int mi  = row >> 4, rr = row & 15;
        const int swz = rr ^ (kc & 15);
        uint4 vh = make_uint4(hi[0], hi[1], hi[2], hi[3]);
        uint4 vl = make_uint4(lo[0], lo[1], lo[2], lo[3]);
        *(uint4*)((char*)As + ((((mi * 2 + 0) * 32 + kc) * 16 + swz) * 16)) = vh;
        *(uint4*)((char*)As + ((((mi * 2 + 1) * 32 + kc) * 16 + swz) * 16)) = vl;
    }
    __syncthreads();

    f32x4 acc[4][4] = {};

    #define LD_A2(mi, s, ks) \
        (*(const short8*)((const char*)As + \
            (((((mi) * 2 + (s)) * 32 + (4 * (ks) + kq)) * 16 + \
              (r16 ^ ((4 * ((ks) & 3) + kq)))) * 16)))

    short8 Ah[2][4], Al[2][4];
    #pragma unroll
    for (int mi = 0; mi < 4; ++mi) { Ah[0][mi] = LD_A2(mi, 0, 0); Al[0][mi] = LD_A2(mi, 1, 0); }

    #pragma unroll
    for (int ks = 0; ks < 8; ++ks) {
        const int cur = ks & 1, nxt = cur ^ 1;
        if (ks < 7) {
            #pragma unroll
            for (int ni = 0; ni < 4; ++ni) {
                Bh[nxt][ni] = LD_B2(ni, 0, ks + 1);
                Bl[nxt][ni] = LD_B2(ni, 1, ks + 1);
            }
            #pragma unroll
            for (int mi = 0; mi < 4; ++mi) {
                Ah[nxt][mi] = LD_A2(mi, 0, ks + 1);
                Al[nxt][mi] = LD_A2(mi, 1, ks + 1);
            }
        }
        #pragma unroll
        for (int mi = 0; mi < 4; ++mi)
            #pragma unroll
            for (int ni = 0; ni < 4; ++ni) {
                acc[mi][ni] = __builtin_amdgcn_mfma_f32_16x16x32_bf16(
                    Ah[cur][mi], Bh[cur][ni], acc[mi][ni], 0, 0, 0);
                acc[mi][ni] = __builtin_amdgcn_mfma_f32_16x16x32_bf16(
                    Ah[cur][mi], Bl[cur][ni], acc[mi][ni], 0, 0, 0);
                acc[mi][ni] = __builtin_amdgcn_mfma_f32_16x16x32_bf16(
                    Al[cur][mi], Bh[cur][ni], acc[mi][ni], 0, 0, 0);
            }
    }
    #undef LD_A2
    #undef LD_B2

    // epilogue: permuted-layout float4 Wh stores for valid rows
    const int n0 = head * 64;
    float bias[4];
    #pragma unroll
    for (int ni = 0; ni < 4; ++ni) bias[ni] = b[n0 + ni * 16 + r16];

    #pragma unroll
    for (int mi = 0; mi < 4; ++mi) {
        #pragma unroll
        for (int reg = 0; reg < 4; ++reg) {
            const int rloc = mi * 16 + kq * 4 + reg;
            const int n    = nl_sh[rloc];
            if (n >= 0) {
                *(float4*)(Wh + (size_t)n * NCOL + n0 + r16 * 4) =
                    make_float4(acc[mi][0][reg] + bias[0],
                                acc[mi][1][reg] + bias[1],
                                acc[mi][2][reg] + bias[2],
                                acc[mi][3][reg] + bias[3]);
            }
        }
    }
}

// ---------------------------------------------------------------------------
// acc_st: stream tbuf coalesced, re-test cut inline, load ei only for passing
// lanes, wave-cooperative gather of permuted Wh[col], atomicAdd out.
// ---------------------------------------------------------------------------
__global__ __launch_bounds__(256) void acc_st_kernel(
    const int* __restrict__ ei, const float* __restrict__ tbuf,
    const float* __restrict__ Wh, const float* __restrict__ coef,
    float* __restrict__ out)
{
    __shared__ float cM[8], cC[8], cCut[8];
    if (threadIdx.x < 8)       cM[threadIdx.x]        = coef[threadIdx.x];
    else if (threadIdx.x < 16) cC[threadIdx.x - 8]    = coef[threadIdx.x];
    else if (threadIdx.x < 24) cCut[threadIdx.x - 16] = coef[threadIdx.x];
    __syncthreads();

    const int lane = threadIdx.x & 63;
    const int e    = blockIdx.x * 256 + threadIdx.x;

    bool pass = false;
    float t[8];
    if (e < N_EDGES) {
        const float4 t0 = *(const float4*)(tbuf + (size_t)e * 8);
        const float4 t1 = *(const float4*)(tbuf + (size_t)e * 8 + 4);
        t[0] = t0.x; t[1] = t0.y; t[2] = t0.z; t[3] = t0.w;
        t[4] = t1.x; t[5] = t1.y; t[6] = t1.z; t[7] = t1.w;
        #pragma unroll
        for (int h = 0; h < 8; ++h) pass |= (t[h] >= cCut[h]);
    }

    int row = 0, col = 0;
    float wgt[8];
    if (pass) {
        row = ei[e];
        col = ei[N_EDGES + e];
        #pragma unroll
        for (int h = 0; h < 8; ++h)
            wgt[h] = __expf(t[h] - cM[h]) * cC[h];
    }

    unsigned long long mask = __ballot(pass);
    while (mask) {
        const int src = (int)__builtin_ctzll(mask);
        mask &= mask - 1;
        const int rb = __shfl(row, src);
        const int cb = __shfl(col, src);
        // permuted Wh row: element (h, o) at h*64 + (o&15)*4 + (o>>4); o == lane
        const float* wc = Wh + (size_t)cb * NCOL + (lane & 15) * 4 + (lane >> 4);
        float acc = 0.f;
        #pragma unroll
        for (int h = 0; h < 8; ++h)
            acc += __shfl(wgt[h], src) * wc[h * 64];
        atomicAdd(out + (size_t)rb * OUT_DIM + lane, acc);
    }
}

// ---------------------------------------------------------------------------
// Fallback acc (no tbuf): r5-verified gather version over elist.
// ---------------------------------------------------------------------------
__global__ __launch_bounds__(256) void acc_kernel(
    const int* __restrict__ ei, const float* __restrict__ s_src,
    const float* __restrict__ s_dst, const float* __restrict__ Wh,
    const float* __restrict__ coef, const int* __restrict__ elist,
    const int* __restrict__ ecount, float* __restrict__ out)
{
    __shared__ float cM[8], cC[8];
    if (threadIdx.x < 8)       cM[threadIdx.x]     = coef[threadIdx.x];
    else if (threadIdx.x < 16) cC[threadIdx.x - 8] = coef[threadIdx.x];
    __syncthreads();

    const int n    = *ecount;
    const int lane = threadIdx.x & 63;

    for (int i = blockIdx.x * 256 + threadIdx.x; ; i += gridDim.x * 256) {
        const bool has = i < n;
        if (!__any(has)) break;

        int row = 0, col = 0;
        float wgt[8];
        if (has) {
            const int e = elist[i];
            row = ei[e];
            col = ei[N_EDGES + e];
            const float4 s0 = *(const float4*)(s_src + row * 8);
            const float4 s1 = *(const float4*)(s_src + row * 8 + 4);
            const float4 d0 = *(const float4*)(s_dst + col * 8);
            const float4 d1 = *(const float4*)(s_dst + col * 8 + 4);
            float t[8] = { s0.x + d0.x, s0.y + d0.y, s0.z + d0.z, s0.w + d0.w,
                           s1.x + d1.x, s1.y + d1.y, s1.z + d1.z, s1.w + d1.w };
            #pragma unroll
            for (int h = 0; h < 8; ++h) {
                t[h] = t[h] > 0.f ? t[h] : 0.01f * t[h];
                wgt[h] = __expf(t[h] - cM[h]) * cC[h];
            }
        }

        unsigned long long mask = __ballot(has);
        while (mask) {
            const int src = (int)__builtin_ctzll(mask);
            mask &= mask - 1;
            const int rb = __shfl(row, src);
            const int cb = __shfl(col, src);
            const float* wc = Wh + (size_t)cb * NCOL + (lane & 15) * 4 + (lane >> 4);
            float acc = 0.f;
            #pragma unroll
            for (int h = 0; h < 8; ++h)
                acc += __shfl(wgt[h], src) * wc[h * 64];
            atomicAdd(out + (size_t)rb * OUT_DIM + lane, acc);
        }
    }
}

// ---------------------------------------------------------------------------
extern "C" void kernel_launch(void* const* d_in, const int* in_sizes, int n_in,
                              void* d_out, int out_size, void* d_ws, size_t ws_size,
                              hipStream_t stream)
{
    const float* x    = (const float*)d_in[0];
    const int*   ei   = (const int*)  d_in[1];
    const float* W    = (const float*)d_in[2];
    const float* b    = (const float*)d_in[3];
    const float* a    = (const float*)d_in[4];
    const float* gate = (const float*)d_in[5];
    float* out = (float*)d_out;

    // workspace (floats): Wh | s_src | s_dst | partial | coef | wp | elist |
    //                     colflag | ecount | ncount | nlist | ug | tbuf
    float* ws      = (float*)d_ws;
    float* Wh      = ws;
    float* s_src   = Wh    + (size_t)N_NODES * NCOL;
    float* s_dst   = s_src + (size_t)N_NODES * HEADS;
    float* partial = s_dst + (size_t)N_NODES * HEADS;
    float* coef    = partial + (size_t)2048 * 16;      // reserve 2048 blocks
    short* wp      = (short*)(coef + 32);              // 512 KB, 16B-aligned
    int*   elist   = (int*)(wp + 262144);              // 800K ints (fallback only)
    int*   colflag = elist + N_EDGES;                  // 50K ints
    int*   ecount  = colflag + N_NODES;                // 1 int
    int*   ncount  = ecount + 1;                       // 1 int
    int*   nlist   = ncount + 1;                       // 50K ints
    float* ug      = (float*)(nlist + N_NODES);        // 4112 floats (u + c)
    float* tbuf    = ug + 4112;                        // 25.6 MB (optional)

    const size_t base_bytes = (size_t)((char*)tbuf - (char*)ws);
    const size_t need_tbuf  = base_bytes + (size_t)N_EDGES * 8 * sizeof(float);
    const bool   use_tbuf   = ws_size >= need_tbuf;

    hipMemsetAsync(d_out, 0, (size_t)N_NODES * OUT_DIM * sizeof(float), stream);
    hipMemsetAsync(colflag, 0, (size_t)(N_NODES + 2) * sizeof(int), stream);

    prep_kernel<<<16, 256, 0, stream>>>(W, b, a, ug);
    packw_kernel<<<32, 256, 0, stream>>>(W, wp);

    score_kernel<<<(N_NODES + 63) / 64, 256, 0, stream>>>(x, ug, s_src, s_dst);

    edge_score_kernel<<<ES_BLOCKS, 256, 0, stream>>>(
        ei, s_src, s_dst, use_tbuf ? tbuf : nullptr, partial);

    finalize_kernel<<<1, 256, 0, stream>>>(partial, gate, coef, ES_BLOCKS);

    if (use_tbuf) {
        mark_flags_kernel<<<(N_EDGES + 255) / 256, 256, 0, stream>>>(
            ei, tbuf, coef, colflag);
        compact_nodes_kernel<<<(N_NODES + 255) / 256, 256, 0, stream>>>(
            colflag, ncount, nlist);
    } else {
        mark_kernel<<<(N_EDGES + 255) / 256, 256, 0, stream>>>(
            ei, s_src, s_dst, coef, elist, colflag, ecount, ncount, nlist);
    }

    whrows_kernel<<<(N_NODES + 63) / 64, 512, 0, stream>>>(
        x, wp, b, nlist, ncount, Wh);

    if (use_tbuf)
        acc_st_kernel<<<(N_EDGES + 255) / 256, 256, 0, stream>>>(
            ei, tbuf, Wh, coef, out);
    else
        acc_kernel<<<256, 256, 0, stream>>>(
            ei, s_src, s_dst, Wh, coef, elist, ecount, out);
}